// Round 8
// baseline (233.164 us; speedup 1.0000x reference)
//
#include <hip/hip_runtime.h>

#define NF 64     // IN == HID
#define OF 32     // OUT

#define NPB 512        // nodes per bucket (power of 2)
#define NPB_SHIFT 9
#define BCAP 12288     // max staged edges per bucket (mean 8192)
#define BIN_CHUNK 4096 // edges per binning block (256 thr x 16)

typedef unsigned int uint;
typedef unsigned short ushort;
typedef __attribute__((ext_vector_type(8))) short bf16x8;
typedef __attribute__((ext_vector_type(4))) float f32x4;

// ---------------- bf16 helpers ----------------

__device__ __forceinline__ ushort f2bf(float f) {
    uint u = __float_as_uint(f);
    uint r = (u + 0x7fffu + ((u >> 16) & 1u)) >> 16;   // RNE
    return (ushort)r;
}
__device__ __forceinline__ float blo(uint u) { return __uint_as_float(u << 16); }
__device__ __forceinline__ float bhi(uint u) { return __uint_as_float(u & 0xffff0000u); }

// ---------------- tiny zero (replaces rocclr fillBuffer) ----------------

__global__ void zero256_kernel(int* __restrict__ p) { p[threadIdx.x] = 0; }

// ---------------- CSR build: bucketed two-pass, no global scatter ----------------

__global__ __launch_bounds__(256) void binning_kernel(
        const int* __restrict__ src, const int* __restrict__ dst, int n_edges,
        int* __restrict__ gcur, uint* __restrict__ stage) {
    __shared__ int hist[256];
    __shared__ int base[256];
    __shared__ int rank[256];
    int t = threadIdx.x;
    hist[t] = 0;
    rank[t] = 0;
    __syncthreads();

    int e0 = blockIdx.x * BIN_CHUNK;
    uint my_pack[16];
    int my_b[16];
#pragma unroll
    for (int j = 0; j < 16; j++) {
        int e = e0 + j * 256 + t;
        if (e < n_edges) {
            int s = src[e];
            int d = dst[e];
            int b = d >> NPB_SHIFT;
            my_b[j] = b;
            my_pack[j] = ((uint)(d & (NPB - 1)) << 17) | (uint)s;
            atomicAdd(&hist[b], 1);
        } else {
            my_b[j] = -1;
        }
    }
    __syncthreads();
    if (hist[t] > 0) base[t] = atomicAdd(&gcur[t], hist[t]);
    __syncthreads();
#pragma unroll
    for (int j = 0; j < 16; j++) {
        if (my_b[j] >= 0) {
            int r = atomicAdd(&rank[my_b[j]], 1);
            int pos = base[my_b[j]] + r;
            if (pos < BCAP) stage[(size_t)my_b[j] * BCAP + pos] = my_pack[j];
        }
    }
}

__global__ void bucket_scan_kernel(const int* __restrict__ gcnt, int* __restrict__ bucket_base, int nb) {
    __shared__ int sh[256];
    int t = threadIdx.x;
    int v = (t < nb) ? gcnt[t] : 0;
    sh[t] = v;
    __syncthreads();
    for (int off = 1; off < 256; off <<= 1) {
        int u = (t >= off) ? sh[t - off] : 0;
        __syncthreads();
        sh[t] += u;
        __syncthreads();
    }
    if (t < nb) bucket_base[t] = sh[t] - v;   // exclusive
    if (t == 255) bucket_base[nb] = sh[255];  // total
}

__global__ __launch_bounds__(256) void build_kernel(
        const uint* __restrict__ stage, const int* __restrict__ gcnt,
        const int* __restrict__ bucket_base,
        int* __restrict__ row_ptr, int* __restrict__ csr, int n, int nb) {
    __shared__ int ncnt[NPB];
    __shared__ int lcur[NPB];
    __shared__ int psum[256];
    __shared__ int lcsr[BCAP];

    int b = blockIdx.x;
    int t = threadIdx.x;
    int cnt = min(gcnt[b], BCAP);
    int node0 = b << NPB_SHIFT;
    int gbase = bucket_base[b];
    const uint* st = stage + (size_t)b * BCAP;

    ncnt[t] = 0;
    ncnt[t + 256] = 0;
    __syncthreads();
    for (int i = t; i < cnt; i += 256)
        atomicAdd(&ncnt[st[i] >> 17], 1);
    __syncthreads();

    int a0 = ncnt[2 * t], a1 = ncnt[2 * t + 1];
    psum[t] = a0 + a1;
    __syncthreads();
    for (int off = 1; off < 256; off <<= 1) {
        int u = (t >= off) ? psum[t - off] : 0;
        __syncthreads();
        psum[t] += u;
        __syncthreads();
    }
    int excl = (t == 0) ? 0 : psum[t - 1];
    int off0 = excl, off1 = excl + a0;
    int g0 = node0 + 2 * t, g1 = node0 + 2 * t + 1;
    if (g0 < n) row_ptr[g0] = gbase + off0;
    if (g1 < n) row_ptr[g1] = gbase + off1;
    lcur[2 * t] = off0;
    lcur[2 * t + 1] = off1;
    __syncthreads();

    for (int i = t; i < cnt; i += 256) {
        uint p = st[i];
        int slot = atomicAdd(&lcur[p >> 17], 1);
        lcsr[slot] = (int)(p & 0x1FFFFu);
    }
    __syncthreads();
    for (int i = t; i < cnt; i += 256)
        csr[gbase + i] = lcsr[i];

    if (b == nb - 1 && t == 0) row_ptr[n] = gbase + cnt;
}

// ---------------- convert x -> bf16 AND prep transposed bf16 weights ----------------

__global__ void convert_prep_kernel(const float* __restrict__ in, ushort* __restrict__ out, int n4,
                                    const float* __restrict__ Ws1, const float* __restrict__ Wn1,
                                    const float* __restrict__ Ws2, const float* __restrict__ Wn2,
                                    ushort* __restrict__ wt1, ushort* __restrict__ wt2) {
    int i = blockIdx.x * blockDim.x + threadIdx.x;
    if (i < n4) {
        float4 v = *(const float4*)(in + (size_t)i * 4);
        ushort4 o;
        o.x = f2bf(v.x); o.y = f2bf(v.y); o.z = f2bf(v.z); o.w = f2bf(v.w);
        *(ushort4*)(out + (size_t)i * 4) = o;
    }
    if (i < NF * 128) {        // wt1: 64 cols x 128 k
        int c = i >> 7, k = i & 127;
        float v = (k < 64) ? Ws1[k * NF + c] : Wn1[(k - 64) * NF + c];
        wt1[i] = f2bf(v);
    }
    if (i < OF * 128) {        // wt2: 32 cols x 128 k
        int c = i >> 7, k = i & 127;
        float v = (k < 64) ? Ws2[k * OF + c] : Wn2[(k - 64) * OF + c];
        wt2[i] = f2bf(v);
    }
}

// ---------------- fused gather + MFMA layers ----------------
// Per wave: gather the 16-node tile's mean-aggregate rows into a 2KB per-wave LDS
// tile (bf16, XOR-swizzled 16B chunks), then MFMA [self|agg] @ Wt^T.
//
// Gather layout: half = lane>>5 (node of pair), es = (lane>>4)&1 (edge slot),
// fq = lane&15 (8B feature quad). 8 edges in flight per pair; per-lane csr loads
// (same-address -> broadcast, L1-hot); reduce = one shfl_xor(16) per acc.
// LDS swizzle: byte = nl*128 + (chunk16 ^ ((nl&7)<<4)) -> ds_read_b128 2-way only.

__device__ __forceinline__ void gather_tile(
        const ushort* __restrict__ feat, const int* __restrict__ rp,
        const int* __restrict__ csr, int r0, int n, int lane,
        char* __restrict__ tile /* 2KB */) {
    int half = lane >> 5;
    int es = (lane >> 4) & 1;
    int fq = lane & 15;
    for (int p = 0; p < 8; p++) {
        int node = r0 + p * 2 + half;
        int beg = 0, end = 0;
        if (node < n) { beg = rp[node]; end = rp[node + 1]; }
        float a0 = 0.f, a1 = 0.f, a2 = 0.f, a3 = 0.f;
        for (int o = beg; o < end; o += 8) {
            int e0 = o + es, e1 = o + 2 + es, e2 = o + 4 + es, e3 = o + 6 + es;
            uint2 v0 = {0u,0u}, v1 = {0u,0u}, v2 = {0u,0u}, v3 = {0u,0u};
            if (e0 < end) v0 = *(const uint2*)(feat + (size_t)csr[e0] * NF + fq * 4);
            if (e1 < end) v1 = *(const uint2*)(feat + (size_t)csr[e1] * NF + fq * 4);
            if (e2 < end) v2 = *(const uint2*)(feat + (size_t)csr[e2] * NF + fq * 4);
            if (e3 < end) v3 = *(const uint2*)(feat + (size_t)csr[e3] * NF + fq * 4);
            a0 += (blo(v0.x) + blo(v1.x)) + (blo(v2.x) + blo(v3.x));
            a1 += (bhi(v0.x) + bhi(v1.x)) + (bhi(v2.x) + bhi(v3.x));
            a2 += (blo(v0.y) + blo(v1.y)) + (blo(v2.y) + blo(v3.y));
            a3 += (bhi(v0.y) + bhi(v1.y)) + (bhi(v2.y) + bhi(v3.y));
        }
        a0 += __shfl_xor(a0, 16);
        a1 += __shfl_xor(a1, 16);
        a2 += __shfl_xor(a2, 16);
        a3 += __shfl_xor(a3, 16);
        if (es == 0) {
            float inv = 1.0f / (float)max(end - beg, 1);
            int nl = p * 2 + half;
            uint2 o2;
            o2.x = (uint)f2bf(a0 * inv) | ((uint)f2bf(a1 * inv) << 16);
            o2.y = (uint)f2bf(a2 * inv) | ((uint)f2bf(a3 * inv) << 16);
            *(uint2*)(tile + nl * 128 + ((fq * 8) ^ ((nl & 7) << 4))) = o2;
        }
    }
}

// layer1: hb = bf16(relu([xb|agg(xb)] @ Wt1^T + b1))
__global__ __launch_bounds__(256) void layer1_kernel(
        const ushort* __restrict__ xb,
        const int* __restrict__ rp, const int* __restrict__ csr,
        const ushort* __restrict__ wt,   // [64][128]
        const float* __restrict__ bias,  // [64]
        ushort* __restrict__ hb, int n, int ntiles) {
    __shared__ char tiles[4][2048];
    int lane = threadIdx.x & 63;
    int wslot = threadIdx.x >> 6;
    char* tile = tiles[wslot];
    int col = lane & 15, kg = lane >> 4;
    int wid = blockIdx.x * 4 + wslot;
    int nw = gridDim.x * 4;

    bf16x8 bfrag[4][4];
#pragma unroll
    for (int ct = 0; ct < 4; ct++)
#pragma unroll
        for (int kt = 0; kt < 4; kt++)
            bfrag[ct][kt] = *(const bf16x8*)(wt + ((ct * 16 + col) * 128 + kt * 32 + kg * 8));
    float bias_v[4];
#pragma unroll
    for (int ct = 0; ct < 4; ct++) bias_v[ct] = bias[ct * 16 + col];

    for (int t = wid; t < ntiles; t += nw) {
        int r0 = t * 16;
        gather_tile(xb, rp, csr, r0, n, lane, tile);

        int row = min(r0 + col, n - 1);
        const ushort* xrow = xb + (size_t)row * NF;
        const char* trow = tile + col * 128;
        int sw = (col & 7) << 4;
        bf16x8 afrag[4];
        afrag[0] = *(const bf16x8*)(xrow + kg * 8);
        afrag[1] = *(const bf16x8*)(xrow + 32 + kg * 8);
        afrag[2] = *(const bf16x8*)(trow + ((kg * 16) ^ sw));
        afrag[3] = *(const bf16x8*)(trow + ((64 + kg * 16) ^ sw));
#pragma unroll
        for (int ct = 0; ct < 4; ct++) {
            f32x4 c = {0.f, 0.f, 0.f, 0.f};
#pragma unroll
            for (int kt = 0; kt < 4; kt++)
                c = __builtin_amdgcn_mfma_f32_16x16x32_bf16(afrag[kt], bfrag[ct][kt], c, 0, 0, 0);
#pragma unroll
            for (int rg = 0; rg < 4; rg++) {
                int ro = r0 + kg * 4 + rg;
                if (ro < n) {
                    float v = c[rg] + bias_v[ct];
                    hb[(size_t)ro * NF + ct * 16 + col] = f2bf(fmaxf(v, 0.f));
                }
            }
        }
    }
}

// layer2: out = [hb|agg(hb)] @ Wt2^T + b2 (fp32, no relu)
__global__ __launch_bounds__(256) void layer2_kernel(
        const ushort* __restrict__ hb,
        const int* __restrict__ rp, const int* __restrict__ csr,
        const ushort* __restrict__ wt,   // [32][128]
        const float* __restrict__ bias,  // [32]
        float* __restrict__ out, int n, int ntiles) {
    __shared__ char tiles[4][2048];
    int lane = threadIdx.x & 63;
    int wslot = threadIdx.x >> 6;
    char* tile = tiles[wslot];
    int col = lane & 15, kg = lane >> 4;
    int wid = blockIdx.x * 4 + wslot;
    int nw = gridDim.x * 4;

    bf16x8 bfrag[2][4];
#pragma unroll
    for (int ct = 0; ct < 2; ct++)
#pragma unroll
        for (int kt = 0; kt < 4; kt++)
            bfrag[ct][kt] = *(const bf16x8*)(wt + ((ct * 16 + col) * 128 + kt * 32 + kg * 8));
    float bias_v[2];
#pragma unroll
    for (int ct = 0; ct < 2; ct++) bias_v[ct] = bias[ct * 16 + col];

    for (int t = wid; t < ntiles; t += nw) {
        int r0 = t * 16;
        gather_tile(hb, rp, csr, r0, n, lane, tile);

        int row = min(r0 + col, n - 1);
        const ushort* hrow = hb + (size_t)row * NF;
        const char* trow = tile + col * 128;
        int sw = (col & 7) << 4;
        bf16x8 afrag[4];
        afrag[0] = *(const bf16x8*)(hrow + kg * 8);
        afrag[1] = *(const bf16x8*)(hrow + 32 + kg * 8);
        afrag[2] = *(const bf16x8*)(trow + ((kg * 16) ^ sw));
        afrag[3] = *(const bf16x8*)(trow + ((64 + kg * 16) ^ sw));
#pragma unroll
        for (int ct = 0; ct < 2; ct++) {
            f32x4 c = {0.f, 0.f, 0.f, 0.f};
#pragma unroll
            for (int kt = 0; kt < 4; kt++)
                c = __builtin_amdgcn_mfma_f32_16x16x32_bf16(afrag[kt], bfrag[ct][kt], c, 0, 0, 0);
#pragma unroll
            for (int rg = 0; rg < 4; rg++) {
                int ro = r0 + kg * 4 + rg;
                if (ro < n) out[(size_t)ro * OF + ct * 16 + col] = c[rg] + bias_v[ct];
            }
        }
    }
}

// ---------------- launch ----------------

extern "C" void kernel_launch(void* const* d_in, const int* in_sizes, int n_in,
                              void* d_out, int out_size, void* d_ws, size_t ws_size,
                              hipStream_t stream) {
    const float* x   = (const float*)d_in[0];
    const int*   src = (const int*)d_in[1];
    const int*   dst = (const int*)d_in[2];
    const float* Ws1 = (const float*)d_in[3];
    const float* Wn1 = (const float*)d_in[4];
    const float* b1  = (const float*)d_in[5];
    const float* Ws2 = (const float*)d_in[6];
    const float* Wn2 = (const float*)d_in[7];
    const float* b2  = (const float*)d_in[8];
    float* out = (float*)d_out;

    int n_nodes = in_sizes[0] / NF;   // 100000
    int n_edges = in_sizes[1];        // 1600000
    int nb = (n_nodes + NPB - 1) >> NPB_SHIFT;   // 196 buckets

    // Workspace: gcur(256) | bucket_base(257) | row_ptr(n+1) | csr(E) | xb | hb | stage | wt1 | wt2
    auto align4k = [](size_t v) { return (v + 4095) & ~(size_t)4095; };
    char* ws = (char*)d_ws;
    size_t gcur_b  = align4k(256 * 4);
    size_t bb_b    = align4k(257 * 4);
    size_t rp_b    = align4k(((size_t)n_nodes + 1) * 4);
    size_t csr_b   = align4k((size_t)n_edges * 4);
    size_t xb_b    = align4k((size_t)n_nodes * NF * 2);
    size_t hb_b    = xb_b;
    size_t stage_b = align4k((size_t)nb * BCAP * 4);
    int* gcur        = (int*)ws;
    int* bucket_base = (int*)(ws + gcur_b);
    int* row_ptr     = (int*)(ws + gcur_b + bb_b);
    int* csr         = (int*)(ws + gcur_b + bb_b + rp_b);
    ushort* xb       = (ushort*)(ws + gcur_b + bb_b + rp_b + csr_b);
    ushort* hb       = (ushort*)(ws + gcur_b + bb_b + rp_b + csr_b + xb_b);
    uint*   stage    = (uint*)(ws + gcur_b + bb_b + rp_b + csr_b + xb_b + hb_b);
    ushort* wt1      = (ushort*)(ws + gcur_b + bb_b + rp_b + csr_b + xb_b + hb_b + stage_b);
    ushort* wt2      = wt1 + NF * 128;

    int bin_blocks = (n_edges + BIN_CHUNK - 1) / BIN_CHUNK;   // 391
    int n4      = n_nodes * NF / 4;
    int cblocks = (n4 + 255) / 256;
    int ntiles  = (n_nodes + 15) / 16;   // 6250
    int lblocks = 1024;                  // 4096 waves, grid-stride over tiles

    zero256_kernel<<<1, 256, 0, stream>>>(gcur);
    convert_prep_kernel<<<cblocks, 256, 0, stream>>>(x, xb, n4, Ws1, Wn1, Ws2, Wn2, wt1, wt2);
    binning_kernel<<<bin_blocks, 256, 0, stream>>>(src, dst, n_edges, gcur, stage);
    bucket_scan_kernel<<<1, 256, 0, stream>>>(gcur, bucket_base, nb);
    build_kernel<<<nb, 256, 0, stream>>>(stage, gcur, bucket_base, row_ptr, csr, n_nodes, nb);

    layer1_kernel<<<lblocks, 256, 0, stream>>>(xb, row_ptr, csr, wt1, b1, hb, n_nodes, ntiles);
    layer2_kernel<<<lblocks, 256, 0, stream>>>(hb, row_ptr, csr, wt2, b2, out, n_nodes, ntiles);
}

// Round 9
// 198.236 us; speedup vs baseline: 1.1762x; 1.1762x over previous
//
#include <hip/hip_runtime.h>

#define NF 64     // IN == HID
#define OF 32     // OUT

#define NPB 512        // nodes per bucket (power of 2)
#define NPB_SHIFT 9
#define BCAP 12288     // max staged edges per bucket (mean 8192)
#define BIN_CHUNK 4096 // edges per binning block (256 thr x 16)

typedef unsigned int uint;
typedef unsigned short ushort;
typedef __attribute__((ext_vector_type(8))) short bf16x8;
typedef __attribute__((ext_vector_type(4))) float f32x4;

// ---------------- bf16 helpers ----------------

__device__ __forceinline__ ushort f2bf(float f) {
    uint u = __float_as_uint(f);
    uint r = (u + 0x7fffu + ((u >> 16) & 1u)) >> 16;   // RNE
    return (ushort)r;
}
__device__ __forceinline__ float blo(uint u) { return __uint_as_float(u << 16); }
__device__ __forceinline__ float bhi(uint u) { return __uint_as_float(u & 0xffff0000u); }

// ---------------- tiny zero (1KB hipMemsetAsync showed as a 41us dispatch!) ----------------

__global__ void zero256_kernel(int* __restrict__ p) { p[threadIdx.x] = 0; }

// ---------------- CSR build: bucketed two-pass, no global scatter ----------------

__global__ __launch_bounds__(256) void binning_kernel(
        const int* __restrict__ src, const int* __restrict__ dst, int n_edges,
        int* __restrict__ gcur, uint* __restrict__ stage) {
    __shared__ int hist[256];
    __shared__ int base[256];
    __shared__ int rank[256];
    int t = threadIdx.x;
    hist[t] = 0;
    rank[t] = 0;
    __syncthreads();

    int e0 = blockIdx.x * BIN_CHUNK;
    uint my_pack[16];
    int my_b[16];
#pragma unroll
    for (int j = 0; j < 16; j++) {
        int e = e0 + j * 256 + t;
        if (e < n_edges) {
            int s = src[e];
            int d = dst[e];
            int b = d >> NPB_SHIFT;
            my_b[j] = b;
            my_pack[j] = ((uint)(d & (NPB - 1)) << 17) | (uint)s;
            atomicAdd(&hist[b], 1);
        } else {
            my_b[j] = -1;
        }
    }
    __syncthreads();
    if (hist[t] > 0) base[t] = atomicAdd(&gcur[t], hist[t]);
    __syncthreads();
#pragma unroll
    for (int j = 0; j < 16; j++) {
        if (my_b[j] >= 0) {
            int r = atomicAdd(&rank[my_b[j]], 1);
            int pos = base[my_b[j]] + r;
            if (pos < BCAP) stage[(size_t)my_b[j] * BCAP + pos] = my_pack[j];
        }
    }
}

__global__ void bucket_scan_kernel(const int* __restrict__ gcnt, int* __restrict__ bucket_base, int nb) {
    __shared__ int sh[256];
    int t = threadIdx.x;
    int v = (t < nb) ? gcnt[t] : 0;
    sh[t] = v;
    __syncthreads();
    for (int off = 1; off < 256; off <<= 1) {
        int u = (t >= off) ? sh[t - off] : 0;
        __syncthreads();
        sh[t] += u;
        __syncthreads();
    }
    if (t < nb) bucket_base[t] = sh[t] - v;   // exclusive
    if (t == 255) bucket_base[nb] = sh[255];  // total
}

__global__ __launch_bounds__(256) void build_kernel(
        const uint* __restrict__ stage, const int* __restrict__ gcnt,
        const int* __restrict__ bucket_base,
        int* __restrict__ row_ptr, int* __restrict__ csr, int n, int nb) {
    __shared__ int ncnt[NPB];
    __shared__ int lcur[NPB];
    __shared__ int psum[256];
    __shared__ int lcsr[BCAP];

    int b = blockIdx.x;
    int t = threadIdx.x;
    int cnt = min(gcnt[b], BCAP);
    int node0 = b << NPB_SHIFT;
    int gbase = bucket_base[b];
    const uint* st = stage + (size_t)b * BCAP;

    ncnt[t] = 0;
    ncnt[t + 256] = 0;
    __syncthreads();
    for (int i = t; i < cnt; i += 256)
        atomicAdd(&ncnt[st[i] >> 17], 1);
    __syncthreads();

    int a0 = ncnt[2 * t], a1 = ncnt[2 * t + 1];
    psum[t] = a0 + a1;
    __syncthreads();
    for (int off = 1; off < 256; off <<= 1) {
        int u = (t >= off) ? psum[t - off] : 0;
        __syncthreads();
        psum[t] += u;
        __syncthreads();
    }
    int excl = (t == 0) ? 0 : psum[t - 1];
    int off0 = excl, off1 = excl + a0;
    int g0 = node0 + 2 * t, g1 = node0 + 2 * t + 1;
    if (g0 < n) row_ptr[g0] = gbase + off0;
    if (g1 < n) row_ptr[g1] = gbase + off1;
    lcur[2 * t] = off0;
    lcur[2 * t + 1] = off1;
    __syncthreads();

    for (int i = t; i < cnt; i += 256) {
        uint p = st[i];
        int slot = atomicAdd(&lcur[p >> 17], 1);
        lcsr[slot] = (int)(p & 0x1FFFFu);
    }
    __syncthreads();
    for (int i = t; i < cnt; i += 256)
        csr[gbase + i] = lcsr[i];

    if (b == nb - 1 && t == 0) row_ptr[n] = gbase + cnt;
}

// ---------------- convert x -> bf16 AND prep transposed bf16 weights ----------------

__global__ void convert_prep_kernel(const float* __restrict__ in, ushort* __restrict__ out, int n4,
                                    const float* __restrict__ Ws1, const float* __restrict__ Wn1,
                                    const float* __restrict__ Ws2, const float* __restrict__ Wn2,
                                    ushort* __restrict__ wt1, ushort* __restrict__ wt2) {
    int i = blockIdx.x * blockDim.x + threadIdx.x;
    if (i < n4) {
        float4 v = *(const float4*)(in + (size_t)i * 4);
        ushort4 o;
        o.x = f2bf(v.x); o.y = f2bf(v.y); o.z = f2bf(v.z); o.w = f2bf(v.w);
        *(ushort4*)(out + (size_t)i * 4) = o;
    }
    if (i < NF * 128) {        // wt1: 64 cols x 128 k
        int c = i >> 7, k = i & 127;
        float v = (k < 64) ? Ws1[k * NF + c] : Wn1[(k - 64) * NF + c];
        wt1[i] = f2bf(v);
    }
    if (i < OF * 128) {        // wt2: 32 cols x 128 k
        int c = i >> 7, k = i & 127;
        float v = (k < 64) ? Ws2[k * OF + c] : Wn2[(k - 64) * OF + c];
        wt2[i] = f2bf(v);
    }
}

// ---------------- gather: reduce-free. 4 nodes/wave; 16-lane group per node ----------------
// Lane owns feature quad (8B) of its group's node row. 8 edges in flight per group
// (8 independent uint2 loads/lane); csr[e] loads are group-uniform (broadcast).
// No __shfl anywhere; final write is one coalesced 128B row per node.

__global__ __launch_bounds__(256) void gather_kernel(
        const ushort* __restrict__ feat,
        const int* __restrict__ row_ptr, const int* __restrict__ csr,
        ushort* __restrict__ agg, int n) {
    int lane = threadIdx.x & 63;
    int g = lane >> 4;           // node slot 0..3
    int fq = lane & 15;          // feature quad (8B)
    int wave = blockIdx.x * 4 + (threadIdx.x >> 6);
    int stride = gridDim.x * 16; // total node slots

    for (int n0 = wave * 4 + g; n0 < n; n0 += stride) {
        int beg = row_ptr[n0], end = row_ptr[n0 + 1];
        float a0 = 0.f, a1 = 0.f, a2 = 0.f, a3 = 0.f;
        for (int o = beg; o < end; o += 8) {
#pragma unroll
            for (int j = 0; j < 8; j++) {
                int e = o + j;
                if (e < end) {
                    uint2 v = *(const uint2*)(feat + (size_t)csr[e] * NF + fq * 4);
                    a0 += blo(v.x);
                    a1 += bhi(v.x);
                    a2 += blo(v.y);
                    a3 += bhi(v.y);
                }
            }
        }
        float inv = 1.0f / (float)max(end - beg, 1);
        uint2 o2;
        o2.x = (uint)f2bf(a0 * inv) | ((uint)f2bf(a1 * inv) << 16);
        o2.y = (uint)f2bf(a2 * inv) | ((uint)f2bf(a3 * inv) << 16);
        *(uint2*)(agg + (size_t)n0 * NF + fq * 4) = o2;
    }
}

// ---------------- gemm1: hb = bf16(relu([xb|aggx] @ Wt1^T + b1)), MFMA 16x16x32 ----------------

__global__ __launch_bounds__(256) void gemm1_kernel(
        const ushort* __restrict__ xb, const ushort* __restrict__ aggx,
        const ushort* __restrict__ wt,   // [64][128] bf16, wt[c][k]
        const float* __restrict__ bias,  // [64]
        ushort* __restrict__ hb, int n, int ntiles) {
    int lane = threadIdx.x & 63;
    int col = lane & 15, kg = lane >> 4;
    int wid = blockIdx.x * 4 + (threadIdx.x >> 6);
    int nw = gridDim.x * 4;

    bf16x8 bfrag[4][4];
#pragma unroll
    for (int ct = 0; ct < 4; ct++)
#pragma unroll
        for (int kt = 0; kt < 4; kt++)
            bfrag[ct][kt] = *(const bf16x8*)(wt + ((ct * 16 + col) * 128 + kt * 32 + kg * 8));
    float bias_v[4];
#pragma unroll
    for (int ct = 0; ct < 4; ct++) bias_v[ct] = bias[ct * 16 + col];

    for (int tile = wid; tile < ntiles; tile += nw) {
        int r0 = tile * 16;
        int row = min(r0 + col, n - 1);
        const ushort* xrow = xb + (size_t)row * NF;
        const ushort* arow = aggx + (size_t)row * NF;
        bf16x8 afrag[4];
        afrag[0] = *(const bf16x8*)(xrow + kg * 8);
        afrag[1] = *(const bf16x8*)(xrow + 32 + kg * 8);
        afrag[2] = *(const bf16x8*)(arow + kg * 8);
        afrag[3] = *(const bf16x8*)(arow + 32 + kg * 8);
#pragma unroll
        for (int ct = 0; ct < 4; ct++) {
            f32x4 c = {0.f, 0.f, 0.f, 0.f};
#pragma unroll
            for (int kt = 0; kt < 4; kt++)
                c = __builtin_amdgcn_mfma_f32_16x16x32_bf16(afrag[kt], bfrag[ct][kt], c, 0, 0, 0);
#pragma unroll
            for (int rg = 0; rg < 4; rg++) {
                int ro = r0 + kg * 4 + rg;
                if (ro < n) {
                    float v = c[rg] + bias_v[ct];
                    hb[(size_t)ro * NF + ct * 16 + col] = f2bf(fmaxf(v, 0.f));
                }
            }
        }
    }
}

// ---------------- gemm2: out = [hb|aggh] @ Wt2^T + b2 (fp32 out, no relu) ----------------

__global__ __launch_bounds__(256) void gemm2_kernel(
        const ushort* __restrict__ hb, const ushort* __restrict__ aggh,
        const ushort* __restrict__ wt,   // [32][128] bf16
        const float* __restrict__ bias,  // [32]
        float* __restrict__ out, int n, int ntiles) {
    int lane = threadIdx.x & 63;
    int col = lane & 15, kg = lane >> 4;
    int wid = blockIdx.x * 4 + (threadIdx.x >> 6);
    int nw = gridDim.x * 4;

    bf16x8 bfrag[2][4];
#pragma unroll
    for (int ct = 0; ct < 2; ct++)
#pragma unroll
        for (int kt = 0; kt < 4; kt++)
            bfrag[ct][kt] = *(const bf16x8*)(wt + ((ct * 16 + col) * 128 + kt * 32 + kg * 8));
    float bias_v[2];
#pragma unroll
    for (int ct = 0; ct < 2; ct++) bias_v[ct] = bias[ct * 16 + col];

    for (int tile = wid; tile < ntiles; tile += nw) {
        int r0 = tile * 16;
        int row = min(r0 + col, n - 1);
        const ushort* hrow = hb + (size_t)row * NF;
        const ushort* arow = aggh + (size_t)row * NF;
        bf16x8 afrag[4];
        afrag[0] = *(const bf16x8*)(hrow + kg * 8);
        afrag[1] = *(const bf16x8*)(hrow + 32 + kg * 8);
        afrag[2] = *(const bf16x8*)(arow + kg * 8);
        afrag[3] = *(const bf16x8*)(arow + 32 + kg * 8);
#pragma unroll
        for (int ct = 0; ct < 2; ct++) {
            f32x4 c = {0.f, 0.f, 0.f, 0.f};
#pragma unroll
            for (int kt = 0; kt < 4; kt++)
                c = __builtin_amdgcn_mfma_f32_16x16x32_bf16(afrag[kt], bfrag[ct][kt], c, 0, 0, 0);
#pragma unroll
            for (int rg = 0; rg < 4; rg++) {
                int ro = r0 + kg * 4 + rg;
                if (ro < n) out[(size_t)ro * OF + ct * 16 + col] = c[rg] + bias_v[ct];
            }
        }
    }
}

// ---------------- launch ----------------

extern "C" void kernel_launch(void* const* d_in, const int* in_sizes, int n_in,
                              void* d_out, int out_size, void* d_ws, size_t ws_size,
                              hipStream_t stream) {
    const float* x   = (const float*)d_in[0];
    const int*   src = (const int*)d_in[1];
    const int*   dst = (const int*)d_in[2];
    const float* Ws1 = (const float*)d_in[3];
    const float* Wn1 = (const float*)d_in[4];
    const float* b1  = (const float*)d_in[5];
    const float* Ws2 = (const float*)d_in[6];
    const float* Wn2 = (const float*)d_in[7];
    const float* b2  = (const float*)d_in[8];
    float* out = (float*)d_out;

    int n_nodes = in_sizes[0] / NF;   // 100000
    int n_edges = in_sizes[1];        // 1600000
    int nb = (n_nodes + NPB - 1) >> NPB_SHIFT;   // 196 buckets

    // Workspace: gcur(256) | bucket_base(257) | row_ptr(n+1) | csr(E) | xb | hb | agg | wt1 | wt2
    // stage (nb*BCAP uints, 9.6 MB) aliases agg (12.8 MB): stage dead before gather1 writes agg.
    auto align4k = [](size_t v) { return (v + 4095) & ~(size_t)4095; };
    char* ws = (char*)d_ws;
    size_t gcur_b = align4k(256 * 4);
    size_t bb_b   = align4k(257 * 4);
    size_t rp_b   = align4k(((size_t)n_nodes + 1) * 4);
    size_t csr_b  = align4k((size_t)n_edges * 4);
    size_t xb_b   = align4k((size_t)n_nodes * NF * 2);
    size_t hb_b   = xb_b;
    size_t agg_b  = xb_b;
    int* gcur        = (int*)ws;
    int* bucket_base = (int*)(ws + gcur_b);
    int* row_ptr     = (int*)(ws + gcur_b + bb_b);
    int* csr         = (int*)(ws + gcur_b + bb_b + rp_b);
    ushort* xb       = (ushort*)(ws + gcur_b + bb_b + rp_b + csr_b);
    ushort* hb       = (ushort*)(ws + gcur_b + bb_b + rp_b + csr_b + xb_b);
    ushort* agg      = (ushort*)(ws + gcur_b + bb_b + rp_b + csr_b + xb_b + hb_b);
    uint*   stage    = (uint*)agg;   // alias
    ushort* wt1      = (ushort*)(ws + gcur_b + bb_b + rp_b + csr_b + xb_b + hb_b + agg_b);
    ushort* wt2      = wt1 + NF * 128;

    int bin_blocks = (n_edges + BIN_CHUNK - 1) / BIN_CHUNK;   // 391
    int n4      = n_nodes * NF / 4;
    int cblocks = (n4 + 255) / 256;
    int ntiles  = (n_nodes + 15) / 16;
    int gblocks = 2048;    // gather: 8192 waves x 4 nodes
    int mblocks = 512;     // gemm: 2048 waves, grid-stride over tiles

    zero256_kernel<<<1, 256, 0, stream>>>(gcur);
    convert_prep_kernel<<<cblocks, 256, 0, stream>>>(x, xb, n4, Ws1, Wn1, Ws2, Wn2, wt1, wt2);
    binning_kernel<<<bin_blocks, 256, 0, stream>>>(src, dst, n_edges, gcur, stage);
    bucket_scan_kernel<<<1, 256, 0, stream>>>(gcur, bucket_base, nb);
    build_kernel<<<nb, 256, 0, stream>>>(stage, gcur, bucket_base, row_ptr, csr, n_nodes, nb);

    // Layer 1
    gather_kernel<<<gblocks, 256, 0, stream>>>(xb, row_ptr, csr, agg, n_nodes);
    gemm1_kernel<<<mblocks, 256, 0, stream>>>(xb, agg, wt1, b1, hb, n_nodes, ntiles);

    // Layer 2 (agg region reused after stage is dead)
    gather_kernel<<<gblocks, 256, 0, stream>>>(hb, row_ptr, csr, agg, n_nodes);
    gemm2_kernel<<<mblocks, 256, 0, stream>>>(hb, agg, wt2, b2, out, n_nodes, ntiles);
}

// Round 10
// 159.080 us; speedup vs baseline: 1.4657x; 1.2461x over previous
//
#include <hip/hip_runtime.h>

#define NF 64     // IN == HID
#define OF 32     // OUT

#define NPB 512        // nodes per bucket (power of 2)
#define NPB_SHIFT 9
#define BCAP 12288     // max staged edges per bucket (mean 8192)
#define BIN_CHUNK 4096 // edges per binning block (256 thr x 16)

typedef unsigned int uint;
typedef unsigned short ushort;
typedef __attribute__((ext_vector_type(8))) short bf16x8;
typedef __attribute__((ext_vector_type(4))) float f32x4;

// ---------------- bf16 helpers ----------------

__device__ __forceinline__ ushort f2bf(float f) {
    uint u = __float_as_uint(f);
    uint r = (u + 0x7fffu + ((u >> 16) & 1u)) >> 16;   // RNE
    return (ushort)r;
}
__device__ __forceinline__ float blo(uint u) { return __uint_as_float(u << 16); }
__device__ __forceinline__ float bhi(uint u) { return __uint_as_float(u & 0xffff0000u); }

// ---------------- tiny zero (1KB hipMemsetAsync costs a 41us fill dispatch) ----------------

__global__ void zero256_kernel(int* __restrict__ p) { p[threadIdx.x] = 0; }

// ---------------- CSR build: bucketed two-pass, no global scatter ----------------

__global__ __launch_bounds__(256) void binning_kernel(
        const int* __restrict__ src, const int* __restrict__ dst, int n_edges,
        int* __restrict__ gcur, uint* __restrict__ stage) {
    __shared__ int hist[256];
    __shared__ int base[256];
    __shared__ int rank[256];
    int t = threadIdx.x;
    hist[t] = 0;
    rank[t] = 0;
    __syncthreads();

    int e0 = blockIdx.x * BIN_CHUNK;
    uint my_pack[16];
    int my_b[16];
#pragma unroll
    for (int j = 0; j < 16; j++) {
        int e = e0 + j * 256 + t;
        if (e < n_edges) {
            int s = src[e];
            int d = dst[e];
            int b = d >> NPB_SHIFT;
            my_b[j] = b;
            my_pack[j] = ((uint)(d & (NPB - 1)) << 17) | (uint)s;
            atomicAdd(&hist[b], 1);
        } else {
            my_b[j] = -1;
        }
    }
    __syncthreads();
    if (hist[t] > 0) base[t] = atomicAdd(&gcur[t], hist[t]);
    __syncthreads();
#pragma unroll
    for (int j = 0; j < 16; j++) {
        if (my_b[j] >= 0) {
            int r = atomicAdd(&rank[my_b[j]], 1);
            int pos = base[my_b[j]] + r;
            if (pos < BCAP) stage[(size_t)my_b[j] * BCAP + pos] = my_pack[j];
        }
    }
}

__global__ void bucket_scan_kernel(const int* __restrict__ gcnt, int* __restrict__ bucket_base, int nb) {
    __shared__ int sh[256];
    int t = threadIdx.x;
    int v = (t < nb) ? gcnt[t] : 0;
    sh[t] = v;
    __syncthreads();
    for (int off = 1; off < 256; off <<= 1) {
        int u = (t >= off) ? sh[t - off] : 0;
        __syncthreads();
        sh[t] += u;
        __syncthreads();
    }
    if (t < nb) bucket_base[t] = sh[t] - v;   // exclusive
    if (t == 255) bucket_base[nb] = sh[255];  // total
}

__global__ __launch_bounds__(256) void build_kernel(
        const uint* __restrict__ stage, const int* __restrict__ gcnt,
        const int* __restrict__ bucket_base,
        int* __restrict__ row_ptr, int* __restrict__ csr, int n, int nb) {
    __shared__ int ncnt[NPB];
    __shared__ int lcur[NPB];
    __shared__ int psum[256];
    __shared__ int lcsr[BCAP];

    int b = blockIdx.x;
    int t = threadIdx.x;
    int cnt = min(gcnt[b], BCAP);
    int node0 = b << NPB_SHIFT;
    int gbase = bucket_base[b];
    const uint* st = stage + (size_t)b * BCAP;

    ncnt[t] = 0;
    ncnt[t + 256] = 0;
    __syncthreads();
    for (int i = t; i < cnt; i += 256)
        atomicAdd(&ncnt[st[i] >> 17], 1);
    __syncthreads();

    int a0 = ncnt[2 * t], a1 = ncnt[2 * t + 1];
    psum[t] = a0 + a1;
    __syncthreads();
    for (int off = 1; off < 256; off <<= 1) {
        int u = (t >= off) ? psum[t - off] : 0;
        __syncthreads();
        psum[t] += u;
        __syncthreads();
    }
    int excl = (t == 0) ? 0 : psum[t - 1];
    int off0 = excl, off1 = excl + a0;
    int g0 = node0 + 2 * t, g1 = node0 + 2 * t + 1;
    if (g0 < n) row_ptr[g0] = gbase + off0;
    if (g1 < n) row_ptr[g1] = gbase + off1;
    lcur[2 * t] = off0;
    lcur[2 * t + 1] = off1;
    __syncthreads();

    for (int i = t; i < cnt; i += 256) {
        uint p = st[i];
        int slot = atomicAdd(&lcur[p >> 17], 1);
        lcsr[slot] = (int)(p & 0x1FFFFu);
    }
    __syncthreads();
    for (int i = t; i < cnt; i += 256)
        csr[gbase + i] = lcsr[i];

    if (b == nb - 1 && t == 0) row_ptr[n] = gbase + cnt;
}

// ---------------- convert x -> bf16 AND prep transposed bf16 weights ----------------

__global__ void convert_prep_kernel(const float* __restrict__ in, ushort* __restrict__ out, int n4,
                                    const float* __restrict__ Ws1, const float* __restrict__ Wn1,
                                    const float* __restrict__ Ws2, const float* __restrict__ Wn2,
                                    ushort* __restrict__ wt1, ushort* __restrict__ wt2) {
    int i = blockIdx.x * blockDim.x + threadIdx.x;
    if (i < n4) {
        float4 v = *(const float4*)(in + (size_t)i * 4);
        ushort4 o;
        o.x = f2bf(v.x); o.y = f2bf(v.y); o.z = f2bf(v.z); o.w = f2bf(v.w);
        *(ushort4*)(out + (size_t)i * 4) = o;
    }
    if (i < NF * 128) {        // wt1: 64 cols x 128 k
        int c = i >> 7, k = i & 127;
        float v = (k < 64) ? Ws1[k * NF + c] : Wn1[(k - 64) * NF + c];
        wt1[i] = f2bf(v);
    }
    if (i < OF * 128) {        // wt2: 32 cols x 128 k
        int c = i >> 7, k = i & 127;
        float v = (k < 64) ? Ws2[k * OF + c] : Wn2[(k - 64) * OF + c];
        wt2[i] = f2bf(v);
    }
}

// ---------------- gather: reduce-free, 16-deep load pipeline ----------------
// 4 nodes/wave; 16-lane group per node; lane owns an 8B feature quad.
// Inner round stages 16 edges' loads into registers BEFORE accumulating:
// 16 independent uint2 loads in flight per lane (deg<=16 nodes = one round).
// csr loads are group-uniform (broadcast, L1-hot). No __shfl anywhere.

__global__ __launch_bounds__(256) void gather_kernel(
        const ushort* __restrict__ feat,
        const int* __restrict__ row_ptr, const int* __restrict__ csr,
        ushort* __restrict__ agg, int n) {
    int lane = threadIdx.x & 63;
    int g = lane >> 4;           // node slot 0..3
    int fq = lane & 15;          // feature quad (8B)
    int wave = blockIdx.x * 4 + (threadIdx.x >> 6);
    int stride = gridDim.x * 16; // total node slots

    for (int n0 = wave * 4 + g; n0 < n; n0 += stride) {
        int beg = row_ptr[n0], end = row_ptr[n0 + 1];
        float a0 = 0.f, a1 = 0.f, a2 = 0.f, a3 = 0.f;
        for (int o = beg; o < end; o += 16) {
            uint2 v[16];
#pragma unroll
            for (int j = 0; j < 16; j++) {
                int e = o + j;
                v[j].x = 0u; v[j].y = 0u;
                if (e < end)
                    v[j] = *(const uint2*)(feat + (size_t)csr[e] * NF + fq * 4);
            }
#pragma unroll
            for (int j = 0; j < 16; j++) {
                a0 += blo(v[j].x);
                a1 += bhi(v[j].x);
                a2 += blo(v[j].y);
                a3 += bhi(v[j].y);
            }
        }
        float inv = 1.0f / (float)max(end - beg, 1);
        uint2 o2;
        o2.x = (uint)f2bf(a0 * inv) | ((uint)f2bf(a1 * inv) << 16);
        o2.y = (uint)f2bf(a2 * inv) | ((uint)f2bf(a3 * inv) << 16);
        *(uint2*)(agg + (size_t)n0 * NF + fq * 4) = o2;
    }
}

// ---------------- gemm1: hb = bf16(relu([xb|aggx] @ Wt1^T + b1)), MFMA 16x16x32 ----------------

__global__ __launch_bounds__(256) void gemm1_kernel(
        const ushort* __restrict__ xb, const ushort* __restrict__ aggx,
        const ushort* __restrict__ wt,   // [64][128] bf16, wt[c][k]
        const float* __restrict__ bias,  // [64]
        ushort* __restrict__ hb, int n, int ntiles) {
    int lane = threadIdx.x & 63;
    int col = lane & 15, kg = lane >> 4;
    int wid = blockIdx.x * 4 + (threadIdx.x >> 6);
    int nw = gridDim.x * 4;

    bf16x8 bfrag[4][4];
#pragma unroll
    for (int ct = 0; ct < 4; ct++)
#pragma unroll
        for (int kt = 0; kt < 4; kt++)
            bfrag[ct][kt] = *(const bf16x8*)(wt + ((ct * 16 + col) * 128 + kt * 32 + kg * 8));
    float bias_v[4];
#pragma unroll
    for (int ct = 0; ct < 4; ct++) bias_v[ct] = bias[ct * 16 + col];

    for (int tile = wid; tile < ntiles; tile += nw) {
        int r0 = tile * 16;
        int row = min(r0 + col, n - 1);
        const ushort* xrow = xb + (size_t)row * NF;
        const ushort* arow = aggx + (size_t)row * NF;
        bf16x8 afrag[4];
        afrag[0] = *(const bf16x8*)(xrow + kg * 8);
        afrag[1] = *(const bf16x8*)(xrow + 32 + kg * 8);
        afrag[2] = *(const bf16x8*)(arow + kg * 8);
        afrag[3] = *(const bf16x8*)(arow + 32 + kg * 8);
#pragma unroll
        for (int ct = 0; ct < 4; ct++) {
            f32x4 c = {0.f, 0.f, 0.f, 0.f};
#pragma unroll
            for (int kt = 0; kt < 4; kt++)
                c = __builtin_amdgcn_mfma_f32_16x16x32_bf16(afrag[kt], bfrag[ct][kt], c, 0, 0, 0);
#pragma unroll
            for (int rg = 0; rg < 4; rg++) {
                int ro = r0 + kg * 4 + rg;
                if (ro < n) {
                    float v = c[rg] + bias_v[ct];
                    hb[(size_t)ro * NF + ct * 16 + col] = f2bf(fmaxf(v, 0.f));
                }
            }
        }
    }
}

// ---------------- gemm2: out = [hb|aggh] @ Wt2^T + b2 (fp32 out, no relu) ----------------

__global__ __launch_bounds__(256) void gemm2_kernel(
        const ushort* __restrict__ hb, const ushort* __restrict__ aggh,
        const ushort* __restrict__ wt,   // [32][128] bf16
        const float* __restrict__ bias,  // [32]
        float* __restrict__ out, int n, int ntiles) {
    int lane = threadIdx.x & 63;
    int col = lane & 15, kg = lane >> 4;
    int wid = blockIdx.x * 4 + (threadIdx.x >> 6);
    int nw = gridDim.x * 4;

    bf16x8 bfrag[2][4];
#pragma unroll
    for (int ct = 0; ct < 2; ct++)
#pragma unroll
        for (int kt = 0; kt < 4; kt++)
            bfrag[ct][kt] = *(const bf16x8*)(wt + ((ct * 16 + col) * 128 + kt * 32 + kg * 8));
    float bias_v[2];
#pragma unroll
    for (int ct = 0; ct < 2; ct++) bias_v[ct] = bias[ct * 16 + col];

    for (int tile = wid; tile < ntiles; tile += nw) {
        int r0 = tile * 16;
        int row = min(r0 + col, n - 1);
        const ushort* hrow = hb + (size_t)row * NF;
        const ushort* arow = aggh + (size_t)row * NF;
        bf16x8 afrag[4];
        afrag[0] = *(const bf16x8*)(hrow + kg * 8);
        afrag[1] = *(const bf16x8*)(hrow + 32 + kg * 8);
        afrag[2] = *(const bf16x8*)(arow + kg * 8);
        afrag[3] = *(const bf16x8*)(arow + 32 + kg * 8);
#pragma unroll
        for (int ct = 0; ct < 2; ct++) {
            f32x4 c = {0.f, 0.f, 0.f, 0.f};
#pragma unroll
            for (int kt = 0; kt < 4; kt++)
                c = __builtin_amdgcn_mfma_f32_16x16x32_bf16(afrag[kt], bfrag[ct][kt], c, 0, 0, 0);
#pragma unroll
            for (int rg = 0; rg < 4; rg++) {
                int ro = r0 + kg * 4 + rg;
                if (ro < n) out[(size_t)ro * OF + ct * 16 + col] = c[rg] + bias_v[ct];
            }
        }
    }
}

// ---------------- launch ----------------

extern "C" void kernel_launch(void* const* d_in, const int* in_sizes, int n_in,
                              void* d_out, int out_size, void* d_ws, size_t ws_size,
                              hipStream_t stream) {
    const float* x   = (const float*)d_in[0];
    const int*   src = (const int*)d_in[1];
    const int*   dst = (const int*)d_in[2];
    const float* Ws1 = (const float*)d_in[3];
    const float* Wn1 = (const float*)d_in[4];
    const float* b1  = (const float*)d_in[5];
    const float* Ws2 = (const float*)d_in[6];
    const float* Wn2 = (const float*)d_in[7];
    const float* b2  = (const float*)d_in[8];
    float* out = (float*)d_out;

    int n_nodes = in_sizes[0] / NF;   // 100000
    int n_edges = in_sizes[1];        // 1600000
    int nb = (n_nodes + NPB - 1) >> NPB_SHIFT;   // 196 buckets

    // Workspace: gcur(256) | bucket_base(257) | row_ptr(n+1) | csr(E) | xb | hb | agg | wt1 | wt2
    // stage (nb*BCAP uints, 9.6 MB) aliases agg (12.8 MB): stage dead before gather1 writes agg.
    auto align4k = [](size_t v) { return (v + 4095) & ~(size_t)4095; };
    char* ws = (char*)d_ws;
    size_t gcur_b = align4k(256 * 4);
    size_t bb_b   = align4k(257 * 4);
    size_t rp_b   = align4k(((size_t)n_nodes + 1) * 4);
    size_t csr_b  = align4k((size_t)n_edges * 4);
    size_t xb_b   = align4k((size_t)n_nodes * NF * 2);
    size_t hb_b   = xb_b;
    size_t agg_b  = xb_b;
    int* gcur        = (int*)ws;
    int* bucket_base = (int*)(ws + gcur_b);
    int* row_ptr     = (int*)(ws + gcur_b + bb_b);
    int* csr         = (int*)(ws + gcur_b + bb_b + rp_b);
    ushort* xb       = (ushort*)(ws + gcur_b + bb_b + rp_b + csr_b);
    ushort* hb       = (ushort*)(ws + gcur_b + bb_b + rp_b + csr_b + xb_b);
    ushort* agg      = (ushort*)(ws + gcur_b + bb_b + rp_b + csr_b + xb_b + hb_b);
    uint*   stage    = (uint*)agg;   // alias
    ushort* wt1      = (ushort*)(ws + gcur_b + bb_b + rp_b + csr_b + xb_b + hb_b + agg_b);
    ushort* wt2      = wt1 + NF * 128;

    int bin_blocks = (n_edges + BIN_CHUNK - 1) / BIN_CHUNK;   // 391
    int n4      = n_nodes * NF / 4;
    int cblocks = (n4 + 255) / 256;
    int ntiles  = (n_nodes + 15) / 16;
    int gblocks = 2048;    // gather: 8192 waves x 4 nodes
    int mblocks = 512;     // gemm: 2048 waves, grid-stride over tiles

    zero256_kernel<<<1, 256, 0, stream>>>(gcur);
    convert_prep_kernel<<<cblocks, 256, 0, stream>>>(x, xb, n4, Ws1, Wn1, Ws2, Wn2, wt1, wt2);
    binning_kernel<<<bin_blocks, 256, 0, stream>>>(src, dst, n_edges, gcur, stage);
    bucket_scan_kernel<<<1, 256, 0, stream>>>(gcur, bucket_base, nb);
    build_kernel<<<nb, 256, 0, stream>>>(stage, gcur, bucket_base, row_ptr, csr, n_nodes, nb);

    // Layer 1
    gather_kernel<<<gblocks, 256, 0, stream>>>(xb, row_ptr, csr, agg, n_nodes);
    gemm1_kernel<<<mblocks, 256, 0, stream>>>(xb, agg, wt1, b1, hb, n_nodes, ntiles);

    // Layer 2 (agg region reused after stage is dead)
    gather_kernel<<<gblocks, 256, 0, stream>>>(hb, row_ptr, csr, agg, n_nodes);
    gemm2_kernel<<<mblocks, 256, 0, stream>>>(hb, agg, wt2, b2, out, n_nodes, ntiles);
}

// Round 12
// 138.983 us; speedup vs baseline: 1.6776x; 1.1446x over previous
//
#include <hip/hip_runtime.h>

#define NF 64     // IN == HID
#define OF 32     // OUT

#define NPB 512        // nodes per bucket (power of 2)
#define NPB_SHIFT 9
#define BCAP 12288     // max staged edges per bucket (mean 8192)
#define BIN_CHUNK 4096 // edges per binning block (256 thr x 16)

typedef unsigned int uint;
typedef unsigned short ushort;
typedef __attribute__((ext_vector_type(8))) short bf16x8;
typedef __attribute__((ext_vector_type(4))) float f32x4;

// ---------------- bf16 helpers ----------------

__device__ __forceinline__ ushort f2bf(float f) {
    uint u = __float_as_uint(f);
    uint r = (u + 0x7fffu + ((u >> 16) & 1u)) >> 16;   // RNE
    return (ushort)r;
}
__device__ __forceinline__ float bf2f(ushort b) { return __uint_as_float(((uint)b) << 16); }
__device__ __forceinline__ float blo(uint u) { return __uint_as_float(u << 16); }
__device__ __forceinline__ float bhi(uint u) { return __uint_as_float(u & 0xffff0000u); }

// ---------------- CSR build: bucketed two-pass, no global scatter ----------------

__global__ __launch_bounds__(256) void binning_kernel(
        const int* __restrict__ src, const int* __restrict__ dst, int n_edges,
        int* __restrict__ gcur, uint* __restrict__ stage) {
    __shared__ int hist[256];
    __shared__ int base[256];
    __shared__ int rank[256];
    int t = threadIdx.x;
    hist[t] = 0;
    rank[t] = 0;
    __syncthreads();

    int e0 = blockIdx.x * BIN_CHUNK;
    uint my_pack[16];
    int my_b[16];
#pragma unroll
    for (int j = 0; j < 16; j++) {
        int e = e0 + j * 256 + t;
        if (e < n_edges) {
            int s = src[e];
            int d = dst[e];
            int b = d >> NPB_SHIFT;
            my_b[j] = b;
            my_pack[j] = ((uint)(d & (NPB - 1)) << 17) | (uint)s;
            atomicAdd(&hist[b], 1);
        } else {
            my_b[j] = -1;
        }
    }
    __syncthreads();
    if (hist[t] > 0) base[t] = atomicAdd(&gcur[t], hist[t]);
    __syncthreads();
#pragma unroll
    for (int j = 0; j < 16; j++) {
        if (my_b[j] >= 0) {
            int r = atomicAdd(&rank[my_b[j]], 1);
            int pos = base[my_b[j]] + r;
            if (pos < BCAP) stage[(size_t)my_b[j] * BCAP + pos] = my_pack[j];
        }
    }
}

__global__ void bucket_scan_kernel(const int* __restrict__ gcnt, int* __restrict__ bucket_base, int nb) {
    __shared__ int sh[256];
    int t = threadIdx.x;
    int v = (t < nb) ? gcnt[t] : 0;
    sh[t] = v;
    __syncthreads();
    for (int off = 1; off < 256; off <<= 1) {
        int u = (t >= off) ? sh[t - off] : 0;
        __syncthreads();
        sh[t] += u;
        __syncthreads();
    }
    if (t < nb) bucket_base[t] = sh[t] - v;   // exclusive
    if (t == 255) bucket_base[nb] = sh[255];  // total
}

__global__ __launch_bounds__(256) void build_kernel(
        const uint* __restrict__ stage, const int* __restrict__ gcnt,
        const int* __restrict__ bucket_base,
        int* __restrict__ row_ptr, int* __restrict__ csr, int n, int nb) {
    __shared__ int ncnt[NPB];
    __shared__ int lcur[NPB];
    __shared__ int psum[256];
    __shared__ int lcsr[BCAP];

    int b = blockIdx.x;
    int t = threadIdx.x;
    int cnt = min(gcnt[b], BCAP);
    int node0 = b << NPB_SHIFT;
    int gbase = bucket_base[b];
    const uint* st = stage + (size_t)b * BCAP;

    ncnt[t] = 0;
    ncnt[t + 256] = 0;
    __syncthreads();
    for (int i = t; i < cnt; i += 256)
        atomicAdd(&ncnt[st[i] >> 17], 1);
    __syncthreads();

    int a0 = ncnt[2 * t], a1 = ncnt[2 * t + 1];
    psum[t] = a0 + a1;
    __syncthreads();
    for (int off = 1; off < 256; off <<= 1) {
        int u = (t >= off) ? psum[t - off] : 0;
        __syncthreads();
        psum[t] += u;
        __syncthreads();
    }
    int excl = (t == 0) ? 0 : psum[t - 1];
    int off0 = excl, off1 = excl + a0;
    int g0 = node0 + 2 * t, g1 = node0 + 2 * t + 1;
    if (g0 < n) row_ptr[g0] = gbase + off0;
    if (g1 < n) row_ptr[g1] = gbase + off1;
    lcur[2 * t] = off0;
    lcur[2 * t + 1] = off1;
    __syncthreads();

    for (int i = t; i < cnt; i += 256) {
        uint p = st[i];
        int slot = atomicAdd(&lcur[p >> 17], 1);
        lcsr[slot] = (int)(p & 0x1FFFFu);
    }
    __syncthreads();
    for (int i = t; i < cnt; i += 256)
        csr[gbase + i] = lcsr[i];

    if (b == nb - 1 && t == 0) row_ptr[n] = gbase + cnt;
}

// ---------------- convert x -> bf16, prep transposed bf16 weights, zero gcur ----------------

__global__ void convert_prep_kernel(const float* __restrict__ in, ushort* __restrict__ out, int n4,
                                    const float* __restrict__ Ws1, const float* __restrict__ Wn1,
                                    const float* __restrict__ Ws2, const float* __restrict__ Wn2,
                                    ushort* __restrict__ wt1, ushort* __restrict__ wt2,
                                    int* __restrict__ gcur) {
    int i = blockIdx.x * blockDim.x + threadIdx.x;
    if (blockIdx.x == 0) gcur[threadIdx.x] = 0;
    if (i < n4) {
        float4 v = *(const float4*)(in + (size_t)i * 4);
        ushort4 o;
        o.x = f2bf(v.x); o.y = f2bf(v.y); o.z = f2bf(v.z); o.w = f2bf(v.w);
        *(ushort4*)(out + (size_t)i * 4) = o;
    }
    if (i < NF * 128) {        // wt1: 64 cols x 128 k
        int c = i >> 7, k = i & 127;
        float v = (k < 64) ? Ws1[k * NF + c] : Wn1[(k - 64) * NF + c];
        wt1[i] = f2bf(v);
    }
    if (i < OF * 128) {        // wt2: 32 cols x 128 k (k<64: Ws2, k>=64: Wn2)
        int c = i >> 7, k = i & 127;
        float v = (k < 64) ? Ws2[k * OF + c] : Wn2[(k - 64) * OF + c];
        wt2[i] = f2bf(v);
    }
}

// ---------------- gather: reduce-free, UNCONDITIONAL 16-deep load pipeline ----------------
// FW = row width in ushorts (64 or 32). LPG = FW/4 lanes per group (8B/lane);
// NPW = 64/LPG nodes per wave. Loads clamp the edge index (always in-bounds within
// this node's rows) so all 16 issue before one waitcnt; tail masked at accumulate.

template<int FW>
__global__ __launch_bounds__(256) void gather_kernel(
        const ushort* __restrict__ feat,
        const int* __restrict__ row_ptr, const int* __restrict__ csr,
        ushort* __restrict__ agg, int n) {
    constexpr int LPG = FW / 4;
    constexpr int NPW = 64 / LPG;
    int lane = threadIdx.x & 63;
    int g = lane / LPG;          // node slot
    int fq = lane % LPG;         // 8B feature quad
    int wave = blockIdx.x * 4 + (threadIdx.x >> 6);
    int stride = gridDim.x * 4 * NPW;

    for (int n0 = wave * NPW + g; n0 < n; n0 += stride) {
        int beg = row_ptr[n0], end = row_ptr[n0 + 1];
        float a0 = 0.f, a1 = 0.f, a2 = 0.f, a3 = 0.f;
        for (int o = beg; o < end; o += 16) {
            uint2 v[16];
#pragma unroll
            for (int j = 0; j < 16; j++) {
                int e = min(o + j, end - 1);
                v[j] = *(const uint2*)(feat + (size_t)csr[e] * FW + fq * 4);
            }
#pragma unroll
            for (int j = 0; j < 16; j++) {
                bool ok = (o + j) < end;
                uint vx = ok ? v[j].x : 0u;
                uint vy = ok ? v[j].y : 0u;
                a0 += blo(vx);
                a1 += bhi(vx);
                a2 += blo(vy);
                a3 += bhi(vy);
            }
        }
        float inv = 1.0f / (float)max(end - beg, 1);
        uint2 o2;
        o2.x = (uint)f2bf(a0 * inv) | ((uint)f2bf(a1 * inv) << 16);
        o2.y = (uint)f2bf(a2 * inv) | ((uint)f2bf(a3 * inv) << 16);
        *(uint2*)(agg + (size_t)n0 * FW + fq * 4) = o2;
    }
}

// ---------------- gemm1: hb = bf16(relu([xb|aggx] @ Wt1^T + b1)), MFMA 16x16x32 ----------------

__global__ __launch_bounds__(256) void gemm1_kernel(
        const ushort* __restrict__ xb, const ushort* __restrict__ aggx,
        const ushort* __restrict__ wt,   // [64][128] bf16, wt[c][k]
        const float* __restrict__ bias,  // [64]
        ushort* __restrict__ hb, int n, int ntiles) {
    int lane = threadIdx.x & 63;
    int col = lane & 15, kg = lane >> 4;
    int wid = blockIdx.x * 4 + (threadIdx.x >> 6);
    int nw = gridDim.x * 4;

    bf16x8 bfrag[4][4];
#pragma unroll
    for (int ct = 0; ct < 4; ct++)
#pragma unroll
        for (int kt = 0; kt < 4; kt++)
            bfrag[ct][kt] = *(const bf16x8*)(wt + ((ct * 16 + col) * 128 + kt * 32 + kg * 8));
    float bias_v[4];
#pragma unroll
    for (int ct = 0; ct < 4; ct++) bias_v[ct] = bias[ct * 16 + col];

    for (int tile = wid; tile < ntiles; tile += nw) {
        int r0 = tile * 16;
        int row = min(r0 + col, n - 1);
        const ushort* xrow = xb + (size_t)row * NF;
        const ushort* arow = aggx + (size_t)row * NF;
        bf16x8 afrag[4];
        afrag[0] = *(const bf16x8*)(xrow + kg * 8);
        afrag[1] = *(const bf16x8*)(xrow + 32 + kg * 8);
        afrag[2] = *(const bf16x8*)(arow + kg * 8);
        afrag[3] = *(const bf16x8*)(arow + 32 + kg * 8);
#pragma unroll
        for (int ct = 0; ct < 4; ct++) {
            f32x4 c = {0.f, 0.f, 0.f, 0.f};
#pragma unroll
            for (int kt = 0; kt < 4; kt++)
                c = __builtin_amdgcn_mfma_f32_16x16x32_bf16(afrag[kt], bfrag[ct][kt], c, 0, 0, 0);
#pragma unroll
            for (int rg = 0; rg < 4; rg++) {
                int ro = r0 + kg * 4 + rg;
                if (ro < n) {
                    float v = c[rg] + bias_v[ct];
                    hb[(size_t)ro * NF + ct * 16 + col] = f2bf(fmaxf(v, 0.f));
                }
            }
        }
    }
}

// ---------------- gemm_un2: un2 = bf16(hb @ Wn2^T)  (N x 32, no bias) ----------------
// Wn2 part of wt2 = k 64..127.

__global__ __launch_bounds__(256) void gemm_un2_kernel(
        const ushort* __restrict__ hb,
        const ushort* __restrict__ wt,   // [32][128] bf16
        ushort* __restrict__ un2, int n, int ntiles) {
    int lane = threadIdx.x & 63;
    int col = lane & 15, kg = lane >> 4;
    int wid = blockIdx.x * 4 + (threadIdx.x >> 6);
    int nw = gridDim.x * 4;

    bf16x8 bfrag[2][2];
#pragma unroll
    for (int ct = 0; ct < 2; ct++)
#pragma unroll
        for (int kt = 0; kt < 2; kt++)
            bfrag[ct][kt] = *(const bf16x8*)(wt + ((ct * 16 + col) * 128 + 64 + kt * 32 + kg * 8));

    for (int tile = wid; tile < ntiles; tile += nw) {
        int r0 = tile * 16;
        int row = min(r0 + col, n - 1);
        const ushort* hrow = hb + (size_t)row * NF;
        bf16x8 afrag[2];
        afrag[0] = *(const bf16x8*)(hrow + kg * 8);
        afrag[1] = *(const bf16x8*)(hrow + 32 + kg * 8);
#pragma unroll
        for (int ct = 0; ct < 2; ct++) {
            f32x4 c = {0.f, 0.f, 0.f, 0.f};
#pragma unroll
            for (int kt = 0; kt < 2; kt++)
                c = __builtin_amdgcn_mfma_f32_16x16x32_bf16(afrag[kt], bfrag[ct][kt], c, 0, 0, 0);
#pragma unroll
            for (int rg = 0; rg < 4; rg++) {
                int ro = r0 + kg * 4 + rg;
                if (ro < n) un2[(size_t)ro * OF + ct * 16 + col] = f2bf(c[rg]);
            }
        }
    }
}

// ---------------- gemm2: out = hb @ Ws2^T + b2 + agg_un2 (fp32 out) ----------------

__global__ __launch_bounds__(256) void gemm2_kernel(
        const ushort* __restrict__ hb, const ushort* __restrict__ aggu,
        const ushort* __restrict__ wt,   // [32][128] bf16 (k<64 = Ws2)
        const float* __restrict__ bias,  // [32]
        float* __restrict__ out, int n, int ntiles) {
    int lane = threadIdx.x & 63;
    int col = lane & 15, kg = lane >> 4;
    int wid = blockIdx.x * 4 + (threadIdx.x >> 6);
    int nw = gridDim.x * 4;

    bf16x8 bfrag[2][2];
#pragma unroll
    for (int ct = 0; ct < 2; ct++)
#pragma unroll
        for (int kt = 0; kt < 2; kt++)
            bfrag[ct][kt] = *(const bf16x8*)(wt + ((ct * 16 + col) * 128 + kt * 32 + kg * 8));
    float bias_v[2];
#pragma unroll
    for (int ct = 0; ct < 2; ct++) bias_v[ct] = bias[ct * 16 + col];

    for (int tile = wid; tile < ntiles; tile += nw) {
        int r0 = tile * 16;
        int row = min(r0 + col, n - 1);
        const ushort* hrow = hb + (size_t)row * NF;
        bf16x8 afrag[2];
        afrag[0] = *(const bf16x8*)(hrow + kg * 8);
        afrag[1] = *(const bf16x8*)(hrow + 32 + kg * 8);
#pragma unroll
        for (int ct = 0; ct < 2; ct++) {
            f32x4 c = {0.f, 0.f, 0.f, 0.f};
#pragma unroll
            for (int kt = 0; kt < 2; kt++)
                c = __builtin_amdgcn_mfma_f32_16x16x32_bf16(afrag[kt], bfrag[ct][kt], c, 0, 0, 0);
#pragma unroll
            for (int rg = 0; rg < 4; rg++) {
                int ro = r0 + kg * 4 + rg;
                if (ro < n) {
                    float add = bf2f(aggu[(size_t)ro * OF + ct * 16 + col]);
                    out[(size_t)ro * OF + ct * 16 + col] = c[rg] + bias_v[ct] + add;
                }
            }
        }
    }
}

// ---------------- launch ----------------

extern "C" void kernel_launch(void* const* d_in, const int* in_sizes, int n_in,
                              void* d_out, int out_size, void* d_ws, size_t ws_size,
                              hipStream_t stream) {
    const float* x   = (const float*)d_in[0];
    const int*   src = (const int*)d_in[1];
    const int*   dst = (const int*)d_in[2];
    const float* Ws1 = (const float*)d_in[3];
    const float* Wn1 = (const float*)d_in[4];
    const float* b1  = (const float*)d_in[5];
    const float* Ws2 = (const float*)d_in[6];
    const float* Wn2 = (const float*)d_in[7];
    const float* b2  = (const float*)d_in[8];
    float* out = (float*)d_out;

    int n_nodes = in_sizes[0] / NF;   // 100000
    int n_edges = in_sizes[1];        // 1600000
    int nb = (n_nodes + NPB - 1) >> NPB_SHIFT;   // 196 buckets

    // Workspace: gcur | bucket_base | row_ptr | csr | xb | hb | agg (12.8MB, aliases
    // stage 9.6MB and later aggu 6.4MB) | un2 (6.4MB) | wt1 | wt2
    auto align4k = [](size_t v) { return (v + 4095) & ~(size_t)4095; };
    char* ws = (char*)d_ws;
    size_t gcur_b = align4k(256 * 4);
    size_t bb_b   = align4k(257 * 4);
    size_t rp_b   = align4k(((size_t)n_nodes + 1) * 4);
    size_t csr_b  = align4k((size_t)n_edges * 4);
    size_t xb_b   = align4k((size_t)n_nodes * NF * 2);
    size_t hb_b   = xb_b;
    size_t agg_b  = xb_b;
    size_t un2_b  = align4k((size_t)n_nodes * OF * 2);
    int* gcur        = (int*)ws;
    int* bucket_base = (int*)(ws + gcur_b);
    int* row_ptr     = (int*)(ws + gcur_b + bb_b);
    int* csr         = (int*)(ws + gcur_b + bb_b + rp_b);
    ushort* xb       = (ushort*)(ws + gcur_b + bb_b + rp_b + csr_b);
    ushort* hb       = (ushort*)(ws + gcur_b + bb_b + rp_b + csr_b + xb_b);
    ushort* agg      = (ushort*)(ws + gcur_b + bb_b + rp_b + csr_b + xb_b + hb_b);
    uint*   stage    = (uint*)agg;    // alias (dead before gather1 writes agg)
    ushort* aggu     = agg;           // alias (layer-2 agg, after gemm1 read agg)
    ushort* un2      = (ushort*)(ws + gcur_b + bb_b + rp_b + csr_b + xb_b + hb_b + agg_b);
    ushort* wt1      = (ushort*)(ws + gcur_b + bb_b + rp_b + csr_b + xb_b + hb_b + agg_b + un2_b);
    ushort* wt2      = wt1 + NF * 128;

    int bin_blocks = (n_edges + BIN_CHUNK - 1) / BIN_CHUNK;   // 391
    int n4      = n_nodes * NF / 4;
    int cblocks = (n4 + 255) / 256;
    int ntiles  = (n_nodes + 15) / 16;
    int gblocks = 2048;    // gather: 8192 waves
    int mblocks = 512;     // gemm: 2048 waves

    convert_prep_kernel<<<cblocks, 256, 0, stream>>>(x, xb, n4, Ws1, Wn1, Ws2, Wn2, wt1, wt2, gcur);
    binning_kernel<<<bin_blocks, 256, 0, stream>>>(src, dst, n_edges, gcur, stage);
    bucket_scan_kernel<<<1, 256, 0, stream>>>(gcur, bucket_base, nb);
    build_kernel<<<nb, 256, 0, stream>>>(stage, gcur, bucket_base, row_ptr, csr, n_nodes, nb);

    // Layer 1
    gather_kernel<64><<<gblocks, 256, 0, stream>>>(xb, row_ptr, csr, agg, n_nodes);
    gemm1_kernel<<<mblocks, 256, 0, stream>>>(xb, agg, wt1, b1, hb, n_nodes, ntiles);

    // Layer 2: un2 = hb@Wn2 (narrow), gather un2, out = hb@Ws2 + b2 + agg(un2)
    gemm_un2_kernel<<<mblocks, 256, 0, stream>>>(hb, wt2, un2, n_nodes, ntiles);
    gather_kernel<32><<<gblocks, 256, 0, stream>>>(un2, row_ptr, csr, aggu, n_nodes);
    gemm2_kernel<<<mblocks, 256, 0, stream>>>(hb, aggu, wt2, b2, out, n_nodes, ntiles);
}

// Round 13
// 122.234 us; speedup vs baseline: 1.9075x; 1.1370x over previous
//
#include <hip/hip_runtime.h>

#define NF 64     // IN == HID
#define OF 32     // OUT

#define NPB 512        // nodes per bucket (power of 2)
#define NPB_SHIFT 9
#define BCAP 12288     // max staged edges per bucket (mean 8192)
#define BIN_CHUNK 4096 // edges per binning block (256 thr x 16)

typedef unsigned int uint;
typedef unsigned short ushort;
typedef __attribute__((ext_vector_type(8))) short bf16x8;
typedef __attribute__((ext_vector_type(4))) float f32x4;

// ---------------- bf16 helpers ----------------

__device__ __forceinline__ ushort f2bf(float f) {
    uint u = __float_as_uint(f);
    uint r = (u + 0x7fffu + ((u >> 16) & 1u)) >> 16;   // RNE
    return (ushort)r;
}
__device__ __forceinline__ float bf2f(ushort b) { return __uint_as_float(((uint)b) << 16); }
__device__ __forceinline__ float blo(uint u) { return __uint_as_float(u << 16); }
__device__ __forceinline__ float bhi(uint u) { return __uint_as_float(u & 0xffff0000u); }

// ---------------- CSR build: bucketed two-pass, no global scatter ----------------

__global__ __launch_bounds__(256) void binning_kernel(
        const int* __restrict__ src, const int* __restrict__ dst, int n_edges,
        int* __restrict__ gcur, uint* __restrict__ stage) {
    __shared__ int hist[256];
    __shared__ int base[256];
    __shared__ int rank[256];
    int t = threadIdx.x;
    hist[t] = 0;
    rank[t] = 0;
    __syncthreads();

    int e0 = blockIdx.x * BIN_CHUNK;
    uint my_pack[16];
    int my_b[16];
#pragma unroll
    for (int j = 0; j < 16; j++) {
        int e = e0 + j * 256 + t;
        if (e < n_edges) {
            int s = src[e];
            int d = dst[e];
            int b = d >> NPB_SHIFT;
            my_b[j] = b;
            my_pack[j] = ((uint)(d & (NPB - 1)) << 17) | (uint)s;
            atomicAdd(&hist[b], 1);
        } else {
            my_b[j] = -1;
        }
    }
    __syncthreads();
    if (hist[t] > 0) base[t] = atomicAdd(&gcur[t], hist[t]);
    __syncthreads();
#pragma unroll
    for (int j = 0; j < 16; j++) {
        if (my_b[j] >= 0) {
            int r = atomicAdd(&rank[my_b[j]], 1);
            int pos = base[my_b[j]] + r;
            if (pos < BCAP) stage[(size_t)my_b[j] * BCAP + pos] = my_pack[j];
        }
    }
}

// build: one block per bucket. Inline exclusive scan of bucket counts (nb<=256),
// then per-node counts + scan in LDS -> row_ptr; scatter srcs in LDS; stream out.
__global__ __launch_bounds__(256) void build_kernel(
        const uint* __restrict__ stage, const int* __restrict__ gcnt,
        int* __restrict__ row_ptr, int* __restrict__ csr, int n, int nb) {
    __shared__ int bsc[256];
    __shared__ int ncnt[NPB];
    __shared__ int lcur[NPB];
    __shared__ int psum[256];
    __shared__ int lcsr[BCAP];

    int b = blockIdx.x;
    int t = threadIdx.x;

    // inline scan of bucket counts (inclusive -> exclusive via b-1)
    bsc[t] = (t < nb) ? gcnt[t] : 0;
    __syncthreads();
    for (int off = 1; off < 256; off <<= 1) {
        int u = (t >= off) ? bsc[t - off] : 0;
        __syncthreads();
        bsc[t] += u;
        __syncthreads();
    }
    int gbase = (b == 0) ? 0 : bsc[b - 1];

    int cnt = min(gcnt[b], BCAP);
    int node0 = b << NPB_SHIFT;
    const uint* st = stage + (size_t)b * BCAP;

    ncnt[t] = 0;
    ncnt[t + 256] = 0;
    __syncthreads();
    for (int i = t; i < cnt; i += 256)
        atomicAdd(&ncnt[st[i] >> 17], 1);
    __syncthreads();

    int a0 = ncnt[2 * t], a1 = ncnt[2 * t + 1];
    psum[t] = a0 + a1;
    __syncthreads();
    for (int off = 1; off < 256; off <<= 1) {
        int u = (t >= off) ? psum[t - off] : 0;
        __syncthreads();
        psum[t] += u;
        __syncthreads();
    }
    int excl = (t == 0) ? 0 : psum[t - 1];
    int off0 = excl, off1 = excl + a0;
    int g0 = node0 + 2 * t, g1 = node0 + 2 * t + 1;
    if (g0 < n) row_ptr[g0] = gbase + off0;
    if (g1 < n) row_ptr[g1] = gbase + off1;
    lcur[2 * t] = off0;
    lcur[2 * t + 1] = off1;
    __syncthreads();

    for (int i = t; i < cnt; i += 256) {
        uint p = st[i];
        int slot = atomicAdd(&lcur[p >> 17], 1);
        lcsr[slot] = (int)(p & 0x1FFFFu);
    }
    __syncthreads();
    for (int i = t; i < cnt; i += 256)
        csr[gbase + i] = lcsr[i];

    if (b == nb - 1 && t == 0) row_ptr[n] = bsc[nb - 1];
}

// ---------------- convert x -> bf16, prep transposed bf16 weights, zero gcur ----------------

__global__ void convert_prep_kernel(const float* __restrict__ in, ushort* __restrict__ out, int n4,
                                    const float* __restrict__ Ws1, const float* __restrict__ Wn1,
                                    const float* __restrict__ Ws2, const float* __restrict__ Wn2,
                                    ushort* __restrict__ wt1, ushort* __restrict__ wt2,
                                    int* __restrict__ gcur) {
    int i = blockIdx.x * blockDim.x + threadIdx.x;
    if (blockIdx.x == 0) gcur[threadIdx.x] = 0;
    if (i < n4) {
        float4 v = *(const float4*)(in + (size_t)i * 4);
        ushort4 o;
        o.x = f2bf(v.x); o.y = f2bf(v.y); o.z = f2bf(v.z); o.w = f2bf(v.w);
        *(ushort4*)(out + (size_t)i * 4) = o;
    }
    if (i < NF * 128) {        // wt1: 64 cols x 128 k
        int c = i >> 7, k = i & 127;
        float v = (k < 64) ? Ws1[k * NF + c] : Wn1[(k - 64) * NF + c];
        wt1[i] = f2bf(v);
    }
    if (i < OF * 128) {        // wt2: 32 cols x 128 k (k<64: Ws2, k>=64: Wn2)
        int c = i >> 7, k = i & 127;
        float v = (k < 64) ? Ws2[k * OF + c] : Wn2[(k - 64) * OF + c];
        wt2[i] = f2bf(v);
    }
}

// ---------------- gather: uint4 (16B/lane), full/tail split, 8-deep pipeline ----------------
// LPG = FW/8 lanes per group; NPW = 64/LPG nodes per wave; grid-stride (~3 nodes/slot).
// Full rounds: 8 unconditional csr+uint4 loads batched before accumulate (no masks).
// Tail round: clamp index (in-bounds), mask at accumulate.

template<int FW>
__global__ __launch_bounds__(256) void gather_kernel(
        const ushort* __restrict__ feat,
        const int* __restrict__ row_ptr, const int* __restrict__ csr,
        ushort* __restrict__ agg, int n) {
    constexpr int LPG = FW / 8;
    constexpr int NPW = 64 / LPG;
    int lane = threadIdx.x & 63;
    int g = lane / LPG;
    int fo = (lane % LPG) * 8;   // ushort offset of this lane's 16B chunk
    int wave = blockIdx.x * 4 + (threadIdx.x >> 6);
    int stride = gridDim.x * 4 * NPW;

    for (int n0 = wave * NPW + g; n0 < n; n0 += stride) {
        int beg = row_ptr[n0], end = row_ptr[n0 + 1];
        int cnt = end - beg;
        int full = beg + (cnt & ~7);
        float a0 = 0.f, a1 = 0.f, a2 = 0.f, a3 = 0.f;
        float a4 = 0.f, a5 = 0.f, a6 = 0.f, a7 = 0.f;
        for (int o = beg; o < full; o += 8) {
            uint4 v[8];
#pragma unroll
            for (int j = 0; j < 8; j++)
                v[j] = *(const uint4*)(feat + (size_t)csr[o + j] * FW + fo);
#pragma unroll
            for (int j = 0; j < 8; j++) {
                a0 += blo(v[j].x); a1 += bhi(v[j].x);
                a2 += blo(v[j].y); a3 += bhi(v[j].y);
                a4 += blo(v[j].z); a5 += bhi(v[j].z);
                a6 += blo(v[j].w); a7 += bhi(v[j].w);
            }
        }
        if (full < end) {
            uint4 v[8];
#pragma unroll
            for (int j = 0; j < 8; j++) {
                int e = min(full + j, end - 1);
                v[j] = *(const uint4*)(feat + (size_t)csr[e] * FW + fo);
            }
#pragma unroll
            for (int j = 0; j < 8; j++) {
                bool ok = (full + j) < end;
                uint vx = ok ? v[j].x : 0u, vy = ok ? v[j].y : 0u;
                uint vz = ok ? v[j].z : 0u, vw = ok ? v[j].w : 0u;
                a0 += blo(vx); a1 += bhi(vx);
                a2 += blo(vy); a3 += bhi(vy);
                a4 += blo(vz); a5 += bhi(vz);
                a6 += blo(vw); a7 += bhi(vw);
            }
        }
        float inv = 1.0f / (float)max(cnt, 1);
        uint4 o4;
        o4.x = (uint)f2bf(a0 * inv) | ((uint)f2bf(a1 * inv) << 16);
        o4.y = (uint)f2bf(a2 * inv) | ((uint)f2bf(a3 * inv) << 16);
        o4.z = (uint)f2bf(a4 * inv) | ((uint)f2bf(a5 * inv) << 16);
        o4.w = (uint)f2bf(a6 * inv) | ((uint)f2bf(a7 * inv) << 16);
        *(uint4*)(agg + (size_t)n0 * FW + fo) = o4;
    }
}

// ---------------- gemm1_fused: hb = bf16(relu([xb|aggx]@Wt1^T + b1)); un2 = bf16(hb@Wn2^T) ----
// SWAPPED operands: A = weights (row = out feature), B = node data (col = node).
// D: col = node (lane&15), row = feature (ct*16 + kg*4 + rg) -> lane holds 4 consecutive
// features of one node => packed 8B stores. hb tile bounced through per-wave swizzled LDS
// (same-wave write->read, no barrier) to form B-frags for the fused un2 MFMA.

__global__ __launch_bounds__(256) void gemm1_fused_kernel(
        const ushort* __restrict__ xb, const ushort* __restrict__ aggx,
        const ushort* __restrict__ wt1,  // [64][128]
        const ushort* __restrict__ wt2,  // [32][128] (k>=64 = Wn2)
        const float* __restrict__ b1,    // [64]
        ushort* __restrict__ hb, ushort* __restrict__ un2, int n, int ntiles) {
    __shared__ char tiles[4][2048];
    int lane = threadIdx.x & 63;
    int wslot = threadIdx.x >> 6;
    char* tile = tiles[wslot];
    int col = lane & 15, kg = lane >> 4;
    int wid = blockIdx.x * 4 + wslot;
    int nw = gridDim.x * 4;
    int sw = (col & 7) << 4;

    bf16x8 wfrag[4][4];              // A = Wt1: row = out feature ct*16+col
#pragma unroll
    for (int ct = 0; ct < 4; ct++)
#pragma unroll
        for (int kt = 0; kt < 4; kt++)
            wfrag[ct][kt] = *(const bf16x8*)(wt1 + ((ct * 16 + col) * 128 + kt * 32 + kg * 8));
    bf16x8 wn2frag[2][2];            // A = Wn2 (k>=64 half of wt2)
#pragma unroll
    for (int c2 = 0; c2 < 2; c2++)
#pragma unroll
        for (int kt = 0; kt < 2; kt++)
            wn2frag[c2][kt] = *(const bf16x8*)(wt2 + ((c2 * 16 + col) * 128 + 64 + kt * 32 + kg * 8));
    float4 bias4[4];
#pragma unroll
    for (int ct = 0; ct < 4; ct++) bias4[ct] = *(const float4*)(b1 + ct * 16 + kg * 4);

    for (int t = wid; t < ntiles; t += nw) {
        int r0 = t * 16;
        int row = min(r0 + col, n - 1);
        const ushort* xrow = xb + (size_t)row * NF;
        const ushort* arow = aggx + (size_t)row * NF;
        bf16x8 nfrag[4];             // B = node data, col = node
        nfrag[0] = *(const bf16x8*)(xrow + kg * 8);
        nfrag[1] = *(const bf16x8*)(xrow + 32 + kg * 8);
        nfrag[2] = *(const bf16x8*)(arow + kg * 8);
        nfrag[3] = *(const bf16x8*)(arow + 32 + kg * 8);

        int node = r0 + col;
        bool ok = node < n;
#pragma unroll
        for (int ct = 0; ct < 4; ct++) {
            f32x4 c = {0.f, 0.f, 0.f, 0.f};
#pragma unroll
            for (int kt = 0; kt < 4; kt++)
                c = __builtin_amdgcn_mfma_f32_16x16x32_bf16(wfrag[ct][kt], nfrag[kt], c, 0, 0, 0);
            uint2 pk;
            pk.x = (uint)f2bf(fmaxf(c[0] + bias4[ct].x, 0.f))
                 | ((uint)f2bf(fmaxf(c[1] + bias4[ct].y, 0.f)) << 16);
            pk.y = (uint)f2bf(fmaxf(c[2] + bias4[ct].z, 0.f))
                 | ((uint)f2bf(fmaxf(c[3] + bias4[ct].w, 0.f)) << 16);
            *(uint2*)(tile + col * 128 + ((ct * 32 + kg * 8) ^ sw)) = pk;
            if (ok) *(uint2*)(hb + (size_t)node * NF + ct * 16 + kg * 4) = pk;
        }

        // fused un2 = hb @ Wn2^T : B-frags from swizzled LDS (same-wave, no barrier)
        bf16x8 hfrag[2];
        hfrag[0] = *(const bf16x8*)(tile + col * 128 + ((0 * 64 + kg * 16) ^ sw));
        hfrag[1] = *(const bf16x8*)(tile + col * 128 + ((1 * 64 + kg * 16) ^ sw));
#pragma unroll
        for (int c2 = 0; c2 < 2; c2++) {
            f32x4 c = {0.f, 0.f, 0.f, 0.f};
            c = __builtin_amdgcn_mfma_f32_16x16x32_bf16(wn2frag[c2][0], hfrag[0], c, 0, 0, 0);
            c = __builtin_amdgcn_mfma_f32_16x16x32_bf16(wn2frag[c2][1], hfrag[1], c, 0, 0, 0);
            if (ok) {
                uint2 pk;
                pk.x = (uint)f2bf(c[0]) | ((uint)f2bf(c[1]) << 16);
                pk.y = (uint)f2bf(c[2]) | ((uint)f2bf(c[3]) << 16);
                *(uint2*)(un2 + (size_t)node * OF + c2 * 16 + kg * 4) = pk;
            }
        }
    }
}

// ---------------- gemm2: out = hb @ Ws2^T + b2 + agg_un2 (fp32, float4 stores) ----------------

__global__ __launch_bounds__(256) void gemm2_kernel(
        const ushort* __restrict__ hb, const ushort* __restrict__ aggu,
        const ushort* __restrict__ wt2,  // [32][128] (k<64 = Ws2)
        const float* __restrict__ b2,    // [32]
        float* __restrict__ out, int n, int ntiles) {
    int lane = threadIdx.x & 63;
    int col = lane & 15, kg = lane >> 4;
    int wid = blockIdx.x * 4 + (threadIdx.x >> 6);
    int nw = gridDim.x * 4;

    bf16x8 wfrag[2][2];
#pragma unroll
    for (int ct = 0; ct < 2; ct++)
#pragma unroll
        for (int kt = 0; kt < 2; kt++)
            wfrag[ct][kt] = *(const bf16x8*)(wt2 + ((ct * 16 + col) * 128 + kt * 32 + kg * 8));
    float4 bias4[2];
#pragma unroll
    for (int ct = 0; ct < 2; ct++) bias4[ct] = *(const float4*)(b2 + ct * 16 + kg * 4);

    for (int t = wid; t < ntiles; t += nw) {
        int r0 = t * 16;
        int row = min(r0 + col, n - 1);
        const ushort* hrow = hb + (size_t)row * NF;
        bf16x8 nfrag[2];
        nfrag[0] = *(const bf16x8*)(hrow + kg * 8);
        nfrag[1] = *(const bf16x8*)(hrow + 32 + kg * 8);

        int node = r0 + col;
        bool ok = node < n;
#pragma unroll
        for (int ct = 0; ct < 2; ct++) {
            f32x4 c = {0.f, 0.f, 0.f, 0.f};
            c = __builtin_amdgcn_mfma_f32_16x16x32_bf16(wfrag[ct][0], nfrag[0], c, 0, 0, 0);
            c = __builtin_amdgcn_mfma_f32_16x16x32_bf16(wfrag[ct][1], nfrag[1], c, 0, 0, 0);
            if (ok) {
                uint2 au = *(const uint2*)(aggu + (size_t)node * OF + ct * 16 + kg * 4);
                float4 o;
                o.x = c[0] + bias4[ct].x + blo(au.x);
                o.y = c[1] + bias4[ct].y + bhi(au.x);
                o.z = c[2] + bias4[ct].z + blo(au.y);
                o.w = c[3] + bias4[ct].w + bhi(au.y);
                *(float4*)(out + (size_t)node * OF + ct * 16 + kg * 4) = o;
            }
        }
    }
}

// ---------------- launch ----------------

extern "C" void kernel_launch(void* const* d_in, const int* in_sizes, int n_in,
                              void* d_out, int out_size, void* d_ws, size_t ws_size,
                              hipStream_t stream) {
    const float* x   = (const float*)d_in[0];
    const int*   src = (const int*)d_in[1];
    const int*   dst = (const int*)d_in[2];
    const float* Ws1 = (const float*)d_in[3];
    const float* Wn1 = (const float*)d_in[4];
    const float* b1  = (const float*)d_in[5];
    const float* Ws2 = (const float*)d_in[6];
    const float* Wn2 = (const float*)d_in[7];
    const float* b2  = (const float*)d_in[8];
    float* out = (float*)d_out;

    int n_nodes = in_sizes[0] / NF;   // 100000
    int n_edges = in_sizes[1];        // 1600000
    int nb = (n_nodes + NPB - 1) >> NPB_SHIFT;   // 196 buckets

    // Workspace: gcur | row_ptr | csr | xb | hb | agg (aliases stage + aggu) | un2 | wt1 | wt2
    auto align4k = [](size_t v) { return (v + 4095) & ~(size_t)4095; };
    char* ws = (char*)d_ws;
    size_t gcur_b = align4k(256 * 4);
    size_t rp_b   = align4k(((size_t)n_nodes + 1) * 4);
    size_t csr_b  = align4k((size_t)n_edges * 4);
    size_t xb_b   = align4k((size_t)n_nodes * NF * 2);
    size_t hb_b   = xb_b;
    size_t agg_b  = xb_b;
    size_t un2_b  = align4k((size_t)n_nodes * OF * 2);
    int* gcur        = (int*)ws;
    int* row_ptr     = (int*)(ws + gcur_b);
    int* csr         = (int*)(ws + gcur_b + rp_b);
    ushort* xb       = (ushort*)(ws + gcur_b + rp_b + csr_b);
    ushort* hb       = (ushort*)(ws + gcur_b + rp_b + csr_b + xb_b);
    ushort* agg      = (ushort*)(ws + gcur_b + rp_b + csr_b + xb_b + hb_b);
    uint*   stage    = (uint*)agg;    // alias (dead before gather1 writes agg)
    ushort* aggu     = agg;           // alias (layer-2 agg, after gemm1 consumed aggx)
    ushort* un2      = (ushort*)(ws + gcur_b + rp_b + csr_b + xb_b + hb_b + agg_b);
    ushort* wt1      = (ushort*)(ws + gcur_b + rp_b + csr_b + xb_b + hb_b + agg_b + un2_b);
    ushort* wt2      = wt1 + NF * 128;

    int bin_blocks = (n_edges + BIN_CHUNK - 1) / BIN_CHUNK;   // 391
    int n4      = n_nodes * NF / 4;
    int cblocks = (n4 + 255) / 256;
    int ntiles  = (n_nodes + 15) / 16;
    int mblocks = 512;     // gemms: 2048 waves, grid-stride over tiles

    convert_prep_kernel<<<cblocks, 256, 0, stream>>>(x, xb, n4, Ws1, Wn1, Ws2, Wn2, wt1, wt2, gcur);
    binning_kernel<<<bin_blocks, 256, 0, stream>>>(src, dst, n_edges, gcur, stage);
    build_kernel<<<nb, 256, 0, stream>>>(stage, gcur, row_ptr, csr, n_nodes, nb);

    // Layer 1 (+ fused un2 = hb@Wn2)
    gather_kernel<64><<<1024, 256, 0, stream>>>(xb, row_ptr, csr, agg, n_nodes);
    gemm1_fused_kernel<<<mblocks, 256, 0, stream>>>(xb, agg, wt1, wt2, b1, hb, un2, n_nodes, ntiles);

    // Layer 2: gather un2 (64B rows), out = hb@Ws2 + b2 + agg(un2)
    gather_kernel<32><<<512, 256, 0, stream>>>(un2, row_ptr, csr, aggu, n_nodes);
    gemm2_kernel<<<mblocks, 256, 0, stream>>>(hb, aggu, wt2, b2, out, n_nodes, ntiles);
}

// Round 14
// 115.678 us; speedup vs baseline: 2.0156x; 1.0567x over previous
//
#include <hip/hip_runtime.h>

#define NF 64     // IN == HID
#define OF 32     // OUT

#define NPB 512        // nodes per bucket (power of 2)
#define NPB_SHIFT 9
#define BCAP 12288     // max staged edges per bucket (mean 8192)
#define BIN_CHUNK 4096 // edges per binning block (256 thr x 16)

typedef unsigned int uint;
typedef unsigned short ushort;
typedef __attribute__((ext_vector_type(8))) short bf16x8;
typedef __attribute__((ext_vector_type(4))) float f32x4;

// ---------------- bf16 helpers ----------------

__device__ __forceinline__ ushort f2bf(float f) {
    uint u = __float_as_uint(f);
    uint r = (u + 0x7fffu + ((u >> 16) & 1u)) >> 16;   // RNE
    return (ushort)r;
}
__device__ __forceinline__ float bf2f(ushort b) { return __uint_as_float(((uint)b) << 16); }
__device__ __forceinline__ float blo(uint u) { return __uint_as_float(u << 16); }
__device__ __forceinline__ float bhi(uint u) { return __uint_as_float(u & 0xffff0000u); }

// ---------------- binning: LDS counting-sort, vectorized loads, coalesced stage writes ----

__global__ __launch_bounds__(256) void binning_kernel(
        const int* __restrict__ src, const int* __restrict__ dst, int n_edges,
        int* __restrict__ gcur, uint* __restrict__ stage) {
    __shared__ int hist[256];
    __shared__ int lofs[256];          // exclusive scan of hist
    __shared__ int gbase[256];         // global reservation per bucket
    __shared__ int lrank[256];
    __shared__ uint lsorted[BIN_CHUNK];
    __shared__ unsigned char lbkt[BIN_CHUNK];

    int t = threadIdx.x;
    hist[t] = 0;
    lrank[t] = 0;
    __syncthreads();

    int e0 = blockIdx.x * BIN_CHUNK;
    int base_e = e0 + t * 16;
    int nloc = min(16, max(0, n_edges - base_e));

    uint es[16], ed[16];
    if (nloc == 16) {      // n_edges % 16 == 0 -> every in-range thread is full
#pragma unroll
        for (int q = 0; q < 4; q++) {
            uint4 s4 = *(const uint4*)(src + base_e + q * 4);
            uint4 d4 = *(const uint4*)(dst + base_e + q * 4);
            es[q * 4 + 0] = s4.x; es[q * 4 + 1] = s4.y; es[q * 4 + 2] = s4.z; es[q * 4 + 3] = s4.w;
            ed[q * 4 + 0] = d4.x; ed[q * 4 + 1] = d4.y; ed[q * 4 + 2] = d4.z; ed[q * 4 + 3] = d4.w;
        }
    } else {
        for (int j = 0; j < nloc; j++) {
            es[j] = (uint)src[base_e + j];
            ed[j] = (uint)dst[base_e + j];
        }
    }

    for (int j = 0; j < nloc; j++)
        atomicAdd(&hist[ed[j] >> NPB_SHIFT], 1);
    __syncthreads();

    // exclusive scan of hist -> lofs
    int hv = hist[t];
    lofs[t] = hv;
    __syncthreads();
    for (int off = 1; off < 256; off <<= 1) {
        int u = (t >= off) ? lofs[t - off] : 0;
        __syncthreads();
        lofs[t] += u;
        __syncthreads();
    }
    int incl = lofs[t];
    __syncthreads();
    lofs[t] = incl - hv;   // exclusive
    if (hv > 0) gbase[t] = atomicAdd(&gcur[t], hv);
    __syncthreads();

    // scatter into LDS (counting sort)
    for (int j = 0; j < nloc; j++) {
        int b = ed[j] >> NPB_SHIFT;
        int r = atomicAdd(&lrank[b], 1);
        int pos = lofs[b] + r;
        lsorted[pos] = ((ed[j] & (NPB - 1)) << 17) | es[j];
        lbkt[pos] = (unsigned char)b;
    }
    __syncthreads();

    // coalesced copy-out: contiguous runs per bucket
    int bcnt = min(BIN_CHUNK, n_edges - e0);
    for (int i = t; i < bcnt; i += 256) {
        int b = lbkt[i];
        int pos = gbase[b] + (i - lofs[b]);
        if (pos < BCAP) stage[(size_t)b * BCAP + pos] = lsorted[i];
    }
}

// build: one block per bucket. Inline exclusive scan of bucket counts (nb<=256),
// then per-node counts + scan in LDS -> row_ptr; scatter srcs in LDS; stream out.
__global__ __launch_bounds__(256) void build_kernel(
        const uint* __restrict__ stage, const int* __restrict__ gcnt,
        int* __restrict__ row_ptr, int* __restrict__ csr, int n, int nb) {
    __shared__ int bsc[256];
    __shared__ int ncnt[NPB];
    __shared__ int lcur[NPB];
    __shared__ int psum[256];
    __shared__ int lcsr[BCAP];

    int b = blockIdx.x;
    int t = threadIdx.x;

    bsc[t] = (t < nb) ? gcnt[t] : 0;
    __syncthreads();
    for (int off = 1; off < 256; off <<= 1) {
        int u = (t >= off) ? bsc[t - off] : 0;
        __syncthreads();
        bsc[t] += u;
        __syncthreads();
    }
    int gbase = (b == 0) ? 0 : bsc[b - 1];

    int cnt = min(gcnt[b], BCAP);
    int node0 = b << NPB_SHIFT;
    const uint* st = stage + (size_t)b * BCAP;

    ncnt[t] = 0;
    ncnt[t + 256] = 0;
    __syncthreads();
    for (int i = t; i < cnt; i += 256)
        atomicAdd(&ncnt[st[i] >> 17], 1);
    __syncthreads();

    int a0 = ncnt[2 * t], a1 = ncnt[2 * t + 1];
    psum[t] = a0 + a1;
    __syncthreads();
    for (int off = 1; off < 256; off <<= 1) {
        int u = (t >= off) ? psum[t - off] : 0;
        __syncthreads();
        psum[t] += u;
        __syncthreads();
    }
    int excl = (t == 0) ? 0 : psum[t - 1];
    int off0 = excl, off1 = excl + a0;
    int g0 = node0 + 2 * t, g1 = node0 + 2 * t + 1;
    if (g0 < n) row_ptr[g0] = gbase + off0;
    if (g1 < n) row_ptr[g1] = gbase + off1;
    lcur[2 * t] = off0;
    lcur[2 * t + 1] = off1;
    __syncthreads();

    for (int i = t; i < cnt; i += 256) {
        uint p = st[i];
        int slot = atomicAdd(&lcur[p >> 17], 1);
        lcsr[slot] = (int)(p & 0x1FFFFu);
    }
    __syncthreads();
    for (int i = t; i < cnt; i += 256)
        csr[gbase + i] = lcsr[i];

    if (b == nb - 1 && t == 0) row_ptr[n] = bsc[nb - 1];
}

// ---------------- convert x -> bf16, prep transposed bf16 weights, zero gcur ----------------

__global__ void convert_prep_kernel(const float* __restrict__ in, ushort* __restrict__ out, int n4,
                                    const float* __restrict__ Ws1, const float* __restrict__ Wn1,
                                    const float* __restrict__ Ws2, const float* __restrict__ Wn2,
                                    ushort* __restrict__ wt1, ushort* __restrict__ wt2,
                                    int* __restrict__ gcur) {
    int i = blockIdx.x * blockDim.x + threadIdx.x;
    if (blockIdx.x == 0) gcur[threadIdx.x] = 0;
    if (i < n4) {
        float4 v = *(const float4*)(in + (size_t)i * 4);
        ushort4 o;
        o.x = f2bf(v.x); o.y = f2bf(v.y); o.z = f2bf(v.z); o.w = f2bf(v.w);
        *(ushort4*)(out + (size_t)i * 4) = o;
    }
    if (i < NF * 128) {        // wt1: 64 cols x 128 k
        int c = i >> 7, k = i & 127;
        float v = (k < 64) ? Ws1[k * NF + c] : Wn1[(k - 64) * NF + c];
        wt1[i] = f2bf(v);
    }
    if (i < OF * 128) {        // wt2: 32 cols x 128 k (k<64: Ws2, k>=64: Wn2)
        int c = i >> 7, k = i & 127;
        float v = (k < 64) ? Ws2[k * OF + c] : Wn2[(k - 64) * OF + c];
        wt2[i] = f2bf(v);
    }
}

// ---------------- gather: uint4 (16B/lane), full/tail split, 8-deep pipeline ----------------

template<int FW>
__global__ __launch_bounds__(256) void gather_kernel(
        const ushort* __restrict__ feat,
        const int* __restrict__ row_ptr, const int* __restrict__ csr,
        ushort* __restrict__ agg, int n) {
    constexpr int LPG = FW / 8;
    constexpr int NPW = 64 / LPG;
    int lane = threadIdx.x & 63;
    int g = lane / LPG;
    int fo = (lane % LPG) * 8;   // ushort offset of this lane's 16B chunk
    int wave = blockIdx.x * 4 + (threadIdx.x >> 6);
    int stride = gridDim.x * 4 * NPW;

    for (int n0 = wave * NPW + g; n0 < n; n0 += stride) {
        int beg = row_ptr[n0], end = row_ptr[n0 + 1];
        int cnt = end - beg;
        int full = beg + (cnt & ~7);
        float a0 = 0.f, a1 = 0.f, a2 = 0.f, a3 = 0.f;
        float a4 = 0.f, a5 = 0.f, a6 = 0.f, a7 = 0.f;
        for (int o = beg; o < full; o += 8) {
            uint4 v[8];
#pragma unroll
            for (int j = 0; j < 8; j++)
                v[j] = *(const uint4*)(feat + (size_t)csr[o + j] * FW + fo);
#pragma unroll
            for (int j = 0; j < 8; j++) {
                a0 += blo(v[j].x); a1 += bhi(v[j].x);
                a2 += blo(v[j].y); a3 += bhi(v[j].y);
                a4 += blo(v[j].z); a5 += bhi(v[j].z);
                a6 += blo(v[j].w); a7 += bhi(v[j].w);
            }
        }
        if (full < end) {
            uint4 v[8];
#pragma unroll
            for (int j = 0; j < 8; j++) {
                int e = min(full + j, end - 1);
                v[j] = *(const uint4*)(feat + (size_t)csr[e] * FW + fo);
            }
#pragma unroll
            for (int j = 0; j < 8; j++) {
                bool ok = (full + j) < end;
                uint vx = ok ? v[j].x : 0u, vy = ok ? v[j].y : 0u;
                uint vz = ok ? v[j].z : 0u, vw = ok ? v[j].w : 0u;
                a0 += blo(vx); a1 += bhi(vx);
                a2 += blo(vy); a3 += bhi(vy);
                a4 += blo(vz); a5 += bhi(vz);
                a6 += blo(vw); a7 += bhi(vw);
            }
        }
        float inv = 1.0f / (float)max(cnt, 1);
        uint4 o4;
        o4.x = (uint)f2bf(a0 * inv) | ((uint)f2bf(a1 * inv) << 16);
        o4.y = (uint)f2bf(a2 * inv) | ((uint)f2bf(a3 * inv) << 16);
        o4.z = (uint)f2bf(a4 * inv) | ((uint)f2bf(a5 * inv) << 16);
        o4.w = (uint)f2bf(a6 * inv) | ((uint)f2bf(a7 * inv) << 16);
        *(uint4*)(agg + (size_t)n0 * FW + fo) = o4;
    }
}

// ---------------- gemm1_fused: hb = bf16(relu([xb|aggx]@Wt1^T + b1)); un2 = bf16(hb@Wn2^T) ----
// SWAPPED operands: A = weights (row = out feature), B = node data (col = node).

__global__ __launch_bounds__(256) void gemm1_fused_kernel(
        const ushort* __restrict__ xb, const ushort* __restrict__ aggx,
        const ushort* __restrict__ wt1,  // [64][128]
        const ushort* __restrict__ wt2,  // [32][128] (k>=64 = Wn2)
        const float* __restrict__ b1,    // [64]
        ushort* __restrict__ hb, ushort* __restrict__ un2, int n, int ntiles) {
    __shared__ char tiles[4][2048];
    int lane = threadIdx.x & 63;
    int wslot = threadIdx.x >> 6;
    char* tile = tiles[wslot];
    int col = lane & 15, kg = lane >> 4;
    int wid = blockIdx.x * 4 + wslot;
    int nw = gridDim.x * 4;
    int sw = (col & 7) << 4;

    bf16x8 wfrag[4][4];              // A = Wt1: row = out feature ct*16+col
#pragma unroll
    for (int ct = 0; ct < 4; ct++)
#pragma unroll
        for (int kt = 0; kt < 4; kt++)
            wfrag[ct][kt] = *(const bf16x8*)(wt1 + ((ct * 16 + col) * 128 + kt * 32 + kg * 8));
    bf16x8 wn2frag[2][2];            // A = Wn2 (k>=64 half of wt2)
#pragma unroll
    for (int c2 = 0; c2 < 2; c2++)
#pragma unroll
        for (int kt = 0; kt < 2; kt++)
            wn2frag[c2][kt] = *(const bf16x8*)(wt2 + ((c2 * 16 + col) * 128 + 64 + kt * 32 + kg * 8));
    float4 bias4[4];
#pragma unroll
    for (int ct = 0; ct < 4; ct++) bias4[ct] = *(const float4*)(b1 + ct * 16 + kg * 4);

    for (int t = wid; t < ntiles; t += nw) {
        int r0 = t * 16;
        int row = min(r0 + col, n - 1);
        const ushort* xrow = xb + (size_t)row * NF;
        const ushort* arow = aggx + (size_t)row * NF;
        bf16x8 nfrag[4];             // B = node data, col = node
        nfrag[0] = *(const bf16x8*)(xrow + kg * 8);
        nfrag[1] = *(const bf16x8*)(xrow + 32 + kg * 8);
        nfrag[2] = *(const bf16x8*)(arow + kg * 8);
        nfrag[3] = *(const bf16x8*)(arow + 32 + kg * 8);

        int node = r0 + col;
        bool ok = node < n;
#pragma unroll
        for (int ct = 0; ct < 4; ct++) {
            f32x4 c = {0.f, 0.f, 0.f, 0.f};
#pragma unroll
            for (int kt = 0; kt < 4; kt++)
                c = __builtin_amdgcn_mfma_f32_16x16x32_bf16(wfrag[ct][kt], nfrag[kt], c, 0, 0, 0);
            uint2 pk;
            pk.x = (uint)f2bf(fmaxf(c[0] + bias4[ct].x, 0.f))
                 | ((uint)f2bf(fmaxf(c[1] + bias4[ct].y, 0.f)) << 16);
            pk.y = (uint)f2bf(fmaxf(c[2] + bias4[ct].z, 0.f))
                 | ((uint)f2bf(fmaxf(c[3] + bias4[ct].w, 0.f)) << 16);
            *(uint2*)(tile + col * 128 + ((ct * 32 + kg * 8) ^ sw)) = pk;
            if (ok) *(uint2*)(hb + (size_t)node * NF + ct * 16 + kg * 4) = pk;
        }

        // fused un2 = hb @ Wn2^T : B-frags from swizzled LDS (same-wave, no barrier)
        bf16x8 hfrag[2];
        hfrag[0] = *(const bf16x8*)(tile + col * 128 + ((0 * 64 + kg * 16) ^ sw));
        hfrag[1] = *(const bf16x8*)(tile + col * 128 + ((1 * 64 + kg * 16) ^ sw));
#pragma unroll
        for (int c2 = 0; c2 < 2; c2++) {
            f32x4 c = {0.f, 0.f, 0.f, 0.f};
            c = __builtin_amdgcn_mfma_f32_16x16x32_bf16(wn2frag[c2][0], hfrag[0], c, 0, 0, 0);
            c = __builtin_amdgcn_mfma_f32_16x16x32_bf16(wn2frag[c2][1], hfrag[1], c, 0, 0, 0);
            if (ok) {
                uint2 pk;
                pk.x = (uint)f2bf(c[0]) | ((uint)f2bf(c[1]) << 16);
                pk.y = (uint)f2bf(c[2]) | ((uint)f2bf(c[3]) << 16);
                *(uint2*)(un2 + (size_t)node * OF + c2 * 16 + kg * 4) = pk;
            }
        }
    }
}

// ---------------- gemm2: out = hb @ Ws2^T + b2 + agg_un2 (fp32, float4 stores) ----------------

__global__ __launch_bounds__(256) void gemm2_kernel(
        const ushort* __restrict__ hb, const ushort* __restrict__ aggu,
        const ushort* __restrict__ wt2,  // [32][128] (k<64 = Ws2)
        const float* __restrict__ b2,    // [32]
        float* __restrict__ out, int n, int ntiles) {
    int lane = threadIdx.x & 63;
    int col = lane & 15, kg = lane >> 4;
    int wid = blockIdx.x * 4 + (threadIdx.x >> 6);
    int nw = gridDim.x * 4;

    bf16x8 wfrag[2][2];
#pragma unroll
    for (int ct = 0; ct < 2; ct++)
#pragma unroll
        for (int kt = 0; kt < 2; kt++)
            wfrag[ct][kt] = *(const bf16x8*)(wt2 + ((ct * 16 + col) * 128 + kt * 32 + kg * 8));
    float4 bias4[2];
#pragma unroll
    for (int ct = 0; ct < 2; ct++) bias4[ct] = *(const float4*)(b2 + ct * 16 + kg * 4);

    for (int t = wid; t < ntiles; t += nw) {
        int r0 = t * 16;
        int row = min(r0 + col, n - 1);
        const ushort* hrow = hb + (size_t)row * NF;
        bf16x8 nfrag[2];
        nfrag[0] = *(const bf16x8*)(hrow + kg * 8);
        nfrag[1] = *(const bf16x8*)(hrow + 32 + kg * 8);

        int node = r0 + col;
        bool ok = node < n;
#pragma unroll
        for (int ct = 0; ct < 2; ct++) {
            f32x4 c = {0.f, 0.f, 0.f, 0.f};
            c = __builtin_amdgcn_mfma_f32_16x16x32_bf16(wfrag[ct][0], nfrag[0], c, 0, 0, 0);
            c = __builtin_amdgcn_mfma_f32_16x16x32_bf16(wfrag[ct][1], nfrag[1], c, 0, 0, 0);
            if (ok) {
                uint2 au = *(const uint2*)(aggu + (size_t)node * OF + ct * 16 + kg * 4);
                float4 o;
                o.x = c[0] + bias4[ct].x + blo(au.x);
                o.y = c[1] + bias4[ct].y + bhi(au.x);
                o.z = c[2] + bias4[ct].z + blo(au.y);
                o.w = c[3] + bias4[ct].w + bhi(au.y);
                *(float4*)(out + (size_t)node * OF + ct * 16 + kg * 4) = o;
            }
        }
    }
}

// ---------------- launch ----------------

extern "C" void kernel_launch(void* const* d_in, const int* in_sizes, int n_in,
                              void* d_out, int out_size, void* d_ws, size_t ws_size,
                              hipStream_t stream) {
    const float* x   = (const float*)d_in[0];
    const int*   src = (const int*)d_in[1];
    const int*   dst = (const int*)d_in[2];
    const float* Ws1 = (const float*)d_in[3];
    const float* Wn1 = (const float*)d_in[4];
    const float* b1  = (const float*)d_in[5];
    const float* Ws2 = (const float*)d_in[6];
    const float* Wn2 = (const float*)d_in[7];
    const float* b2  = (const float*)d_in[8];
    float* out = (float*)d_out;

    int n_nodes = in_sizes[0] / NF;   // 100000
    int n_edges = in_sizes[1];        // 1600000
    int nb = (n_nodes + NPB - 1) >> NPB_SHIFT;   // 196 buckets

    // Workspace: gcur | row_ptr | csr | xb | hb | agg (aliases stage + aggu) | un2 | wt1 | wt2
    auto align4k = [](size_t v) { return (v + 4095) & ~(size_t)4095; };
    char* ws = (char*)d_ws;
    size_t gcur_b = align4k(256 * 4);
    size_t rp_b   = align4k(((size_t)n_nodes + 1) * 4);
    size_t csr_b  = align4k((size_t)n_edges * 4);
    size_t xb_b   = align4k((size_t)n_nodes * NF * 2);
    size_t hb_b   = xb_b;
    size_t agg_b  = xb_b;
    size_t un2_b  = align4k((size_t)n_nodes * OF * 2);
    int* gcur        = (int*)ws;
    int* row_ptr     = (int*)(ws + gcur_b);
    int* csr         = (int*)(ws + gcur_b + rp_b);
    ushort* xb       = (ushort*)(ws + gcur_b + rp_b + csr_b);
    ushort* hb       = (ushort*)(ws + gcur_b + rp_b + csr_b + xb_b);
    ushort* agg      = (ushort*)(ws + gcur_b + rp_b + csr_b + xb_b + hb_b);
    uint*   stage    = (uint*)agg;    // alias (dead before gather1 writes agg)
    ushort* aggu     = agg;           // alias (layer-2 agg, after gemm1 consumed aggx)
    ushort* un2      = (ushort*)(ws + gcur_b + rp_b + csr_b + xb_b + hb_b + agg_b);
    ushort* wt1      = (ushort*)(ws + gcur_b + rp_b + csr_b + xb_b + hb_b + agg_b + un2_b);
    ushort* wt2      = wt1 + NF * 128;

    int bin_blocks = (n_edges + BIN_CHUNK - 1) / BIN_CHUNK;   // 391
    int n4      = n_nodes * NF / 4;
    int cblocks = (n4 + 255) / 256;
    int ntiles  = (n_nodes + 15) / 16;
    int mblocks = 512;     // gemms: 2048 waves, grid-stride over tiles

    convert_prep_kernel<<<cblocks, 256, 0, stream>>>(x, xb, n4, Ws1, Wn1, Ws2, Wn2, wt1, wt2, gcur);
    binning_kernel<<<bin_blocks, 256, 0, stream>>>(src, dst, n_edges, gcur, stage);
    build_kernel<<<nb, 256, 0, stream>>>(stage, gcur, row_ptr, csr, n_nodes, nb);

    // Layer 1 (+ fused un2 = hb@Wn2)
    gather_kernel<64><<<2048, 256, 0, stream>>>(xb, row_ptr, csr, agg, n_nodes);
    gemm1_fused_kernel<<<mblocks, 256, 0, stream>>>(xb, agg, wt1, wt2, b1, hb, un2, n_nodes, ntiles);

    // Layer 2: gather un2 (64B rows), out = hb@Ws2 + b2 + agg(un2)
    gather_kernel<32><<<1024, 256, 0, stream>>>(un2, row_ptr, csr, aggu, n_nodes);
    gemm2_kernel<<<mblocks, 256, 0, stream>>>(hb, aggu, wt2, b2, out, n_nodes, ntiles);
}